// Round 1
// baseline (1429.404 us; speedup 1.0000x reference)
//
#include <hip/hip_runtime.h>
#include <hip/hip_bf16.h>
#include <cstdint>
#include <cstddef>

// ---------------- problem constants ----------------
#define BB 512
#define SS 500
#define DD 128
#define TT 499            // scan steps t = 0..498
#define NRB 32            // recurrence blocks (16 rows each)

typedef float  f32x4  __attribute__((ext_vector_type(4)));
typedef short  bf16x8 __attribute__((ext_vector_type(8)));
typedef unsigned short ushort4v __attribute__((ext_vector_type(4)));

// ---------------- workspace layout (bytes) ----------------
// tables
static constexpr size_t OFF_TXQ   = 0;                 // 10000*128*4
static constexpr size_t OFF_TXC   = 5120000;           // 500*128*4
static constexpr size_t OFF_TXQD  = 5376000;           // 100*128*4
static constexpr size_t OFF_TXCD  = 5427200;           // 100*128*4
static constexpr size_t OFF_TKIQD = 5478400;           // 100*128*4
static constexpr size_t OFF_TKICD = 5529600;           // 100*128*4
static constexpr size_t OFF_TKICO = 5580800;           // 2*128*4 (pad 1024)
static constexpr size_t OFF_TP1   = 5581824;           // 2*128*4 (pad 1024)
static constexpr size_t OFF_TP2   = 5582848;           // 2*128*4 (pad 1024)
static constexpr size_t OFF_WFRAG = 5583872;           // 5*128*128*2
static constexpr size_t OFF_CPK   = 5747712;           // 32*4*500
static constexpr size_t OFF_XCD   = 5812224;           // 500*32*2048*4
static constexpr size_t OFF_XFRAG = 136884224;         // 500*32*2048*2
static constexpr size_t OFF_KIPRE = 202420224;         // 500*32*2048*4
static constexpr size_t OFF_YPART = 333492224;         // 499*32*8*16*4*4
static constexpr size_t TOTAL_WS  = 366194688;

// fallback scratch if harness workspace is too small
__device__ unsigned char g_fb[TOTAL_WS];

// ---------------- helpers ----------------
__device__ __forceinline__ unsigned short f2bf(float f) {
    union { float f; uint32_t u; } v; v.f = f;
    uint32_t u = v.u;
    uint32_t r = u + 0x7FFFu + ((u >> 16) & 1u);
    return (unsigned short)(r >> 16);
}
__device__ __forceinline__ float fsig(float z)  { return 1.0f / (1.0f + __expf(-z)); }
__device__ __forceinline__ float ftanh(float z) { return 1.0f - 2.0f / (__expf(2.0f * z) + 1.0f); }

// ---------------- P1: per-table GEMM products ----------------
// rows: [0,10000) Txq=Eq@Wx0+bx | [10000,10500) Txc | [10500,10600) Txqd | [10600,10700) Txcd
// [10700,10800) TkiQd | [10800,10900) TkiCd | [10900,10902) TkiCo+bki
// [10902,10904) Tp1+bpka1 | [10904,10906) Tp2+bpka2
__global__ __launch_bounds__(128) void k_tables(
    const float* __restrict__ Eq, const float* __restrict__ Ec,
    const float* __restrict__ Eqd, const float* __restrict__ Ecd,
    const float* __restrict__ Ecorr,
    const float* __restrict__ Wx,  const float* __restrict__ bx,
    const float* __restrict__ Wpka1, const float* __restrict__ bpka1,
    const float* __restrict__ Wpka2, const float* __restrict__ bpka2,
    const float* __restrict__ Wki, const float* __restrict__ bki,
    float* __restrict__ Txq, float* __restrict__ Txc,
    float* __restrict__ Txqd, float* __restrict__ Txcd,
    float* __restrict__ TkiQd, float* __restrict__ TkiCd, float* __restrict__ TkiCo,
    float* __restrict__ Tp1, float* __restrict__ Tp2)
{
    int blk = blockIdx.x;
    const float* A; const float* W; const float* bias = nullptr; float* out; int row;
    if      (blk < 10000) { A = Eq;    row = blk;          W = Wx;              bias = bx;    out = Txq;  }
    else if (blk < 10500) { A = Ec;    row = blk - 10000;  W = Wx  + 128*128;                 out = Txc;  }
    else if (blk < 10600) { A = Eqd;   row = blk - 10500;  W = Wx  + 256*128;                 out = Txqd; }
    else if (blk < 10700) { A = Ecd;   row = blk - 10600;  W = Wx  + 384*128;                 out = Txcd; }
    else if (blk < 10800) { A = Eqd;   row = blk - 10700;  W = Wki + 256*128;                 out = TkiQd;}
    else if (blk < 10900) { A = Ecd;   row = blk - 10800;  W = Wki + 384*128;                 out = TkiCd;}
    else if (blk < 10902) { A = Ecorr; row = blk - 10900;  W = Wki + 128*128;   bias = bki;   out = TkiCo;}
    else if (blk < 10904) { A = Ecorr; row = blk - 10902;  W = Wpka1 + 128*128; bias = bpka1; out = Tp1;  }
    else                  { A = Ecorr; row = blk - 10904;  W = Wpka2 + 128*128; bias = bpka2; out = Tp2;  }

    __shared__ float a[128];
    int c = threadIdx.x;
    a[c] = A[row * 128 + c];
    __syncthreads();
    float acc = bias ? bias[c] : 0.0f;
    #pragma unroll 8
    for (int k = 0; k < 128; ++k) acc += a[k] * W[k * 128 + c];
    out[row * 128 + c] = acc;
}

// ---------------- P0: weight matrices -> MFMA B-fragments (bf16) ----------------
// frag layout per (m, w, kt): lane l holds W[k = kt*32 + (l>>4)*8 + j][col = 16w + (l&15)], j=0..7
__global__ __launch_bounds__(64) void k_wfrag(
    const float* __restrict__ Wsdf1, const float* __restrict__ Wsdf2,
    const float* __restrict__ Wpka1, const float* __restrict__ Wpka2,
    const float* __restrict__ Wki, unsigned short* __restrict__ wfrag)
{
    int bid = blockIdx.x;                 // 5 * 8 * 4 = 160
    int m = bid >> 5, w = (bid >> 2) & 7, kt = bid & 3;
    const float* W = (m == 0) ? Wsdf1 : (m == 1) ? Wsdf2 : (m == 2) ? Wpka1 : (m == 3) ? Wpka2 : Wki;
    int l = threadIdx.x;
    int cc = w * 16 + (l & 15);
    int k0 = kt * 32 + ((l >> 4) << 3);
    unsigned short v[8];
    #pragma unroll
    for (int j = 0; j < 8; ++j) v[j] = f2bf(W[(size_t)(k0 + j) * 128 + cc]);
    unsigned short* dst = wfrag + ((( (size_t)m * 8 + w) * 4 + kt) * 64 + l) * 8;
    #pragma unroll
    for (int j = 0; j < 8; ++j) dst[j] = v[j];
}

// ---------------- P2: materialize x / kipre in recurrence-friendly layouts ----------------
// grid = 500*32 blocks (bid = t*32 + rb), 512 threads
__global__ __launch_bounds__(512) void k_gather(
    const int* __restrict__ qs, const int* __restrict__ cs,
    const int* __restrict__ qds, const int* __restrict__ cds, const int* __restrict__ corr,
    const float* __restrict__ Txq, const float* __restrict__ Txc,
    const float* __restrict__ Txqd, const float* __restrict__ Txcd,
    const float* __restrict__ TkiQd, const float* __restrict__ TkiCd, const float* __restrict__ TkiCo,
    float* __restrict__ xcd, unsigned short* __restrict__ xfrag,
    float* __restrict__ kipre, unsigned char* __restrict__ cpk)
{
    int bid = blockIdx.x;
    int t = bid >> 5, rb = bid & 31;
    __shared__ float xl[16][128];
    __shared__ float kl[16][128];
    __shared__ int idx[5][16];
    int tid = threadIdx.x;
    if (tid < 80) {
        int which = tid >> 4, row = tid & 15;
        const int* P = (which == 0) ? qs : (which == 1) ? cs : (which == 2) ? qds : (which == 3) ? cds : corr;
        idx[which][row] = P[(size_t)(rb * 16 + row) * SS + t];
    }
    __syncthreads();
    {
        int row = tid >> 5; int c0 = (tid & 31) * 4;
        f32x4 xq = *(const f32x4*)&Txq [(size_t)idx[0][row] * 128 + c0];
        f32x4 xc = *(const f32x4*)&Txc [(size_t)idx[1][row] * 128 + c0];
        f32x4 xd = *(const f32x4*)&Txqd[(size_t)idx[2][row] * 128 + c0];
        f32x4 xe = *(const f32x4*)&Txcd[(size_t)idx[3][row] * 128 + c0];
        f32x4 k1 = *(const f32x4*)&TkiQd[(size_t)idx[2][row] * 128 + c0];
        f32x4 k2 = *(const f32x4*)&TkiCd[(size_t)idx[3][row] * 128 + c0];
        f32x4 k3 = *(const f32x4*)&TkiCo[(size_t)idx[4][row] * 128 + c0];
        #pragma unroll
        for (int i = 0; i < 4; ++i) {
            xl[row][c0 + i] = xq[i] + xc[i] + xd[i] + xe[i];
            kl[row][c0 + i] = k1[i] + k2[i] + k3[i];
        }
    }
    __syncthreads();
    size_t base = (size_t)bid * 2048;
    {   // C/D-layout f32 copies: element (w,l,i) = x[(l>>4)*4+i][w*16+(l&15)]
        int w = tid >> 6, l = tid & 63;
        int g = l >> 4, cc = w * 16 + (l & 15);
        f32x4 o, o2;
        #pragma unroll
        for (int i = 0; i < 4; ++i) { o[i] = xl[g * 4 + i][cc]; o2[i] = kl[g * 4 + i][cc]; }
        *(f32x4*)&xcd[base + (size_t)tid * 4]   = o;
        *(f32x4*)&kipre[base + (size_t)tid * 4] = o2;
    }
    {   // A-frag bf16 copy: element (kt,l,j) = x[l&15][kt*32+(l>>4)*8+j]
        int fo = tid * 4;
        int kt = fo >> 9, l = (fo >> 3) & 63, j0 = fo & 7;
        int row = l & 15, k0 = kt * 32 + ((l >> 4) << 3) + j0;
        ushort4v v;
        #pragma unroll
        for (int jj = 0; jj < 4; ++jj) v[jj] = f2bf(xl[row][k0 + jj]);
        *(ushort4v*)&xfrag[base + fo] = v;
    }
    if (tid < 4) {  // packed correct-bits: byte g holds bits for rows 4g..4g+3
        unsigned char b = 0;
        #pragma unroll
        for (int i = 0; i < 4; ++i) b |= (unsigned char)((idx[4][tid * 4 + i] & 1) << i);
        cpk[(size_t)(rb * 4 + tid) * SS + t] = b;
    }
}

// ---------------- recurrence: 32 blocks x 512 threads (8 waves x 16-col slices) ----------------
__global__ __launch_bounds__(512, 2) void k_rec(
    const float* __restrict__ xcd, const unsigned short* __restrict__ xfrag,
    const float* __restrict__ kipre, const unsigned char* __restrict__ cpkg,
    const unsigned short* __restrict__ wfrag,
    const float* __restrict__ Tp1, const float* __restrict__ Tp2,
    const float* __restrict__ bsdf1, const float* __restrict__ bsdf2,
    const float* __restrict__ h0, float* __restrict__ ypart)
{
    int rb = blockIdx.x;
    int tid = threadIdx.x;
    int w = tid >> 6, l = tid & 63;
    int g = l >> 4, cl = l & 15;
    int col = w * 16 + cl;

    __shared__ __align__(16) unsigned short dbuf[2048];
    __shared__ __align__(16) unsigned short sbuf[2048];

    // weight B-fragments (5 matrices x 4 k-tiles)
    bf16x8 wf[5][4];
    #pragma unroll
    for (int m = 0; m < 5; ++m)
        #pragma unroll
        for (int kt = 0; kt < 4; ++kt)
            wf[m][kt] = *(const bf16x8*)(wfrag + ((((size_t)m * 8 + w) * 4 + kt) * 64 + l) * 8);

    float bs1 = bsdf1[col], bs2 = bsdf2[col];
    float tp1a = Tp1[col], tp1b = Tp1[128 + col];
    float tp2a = Tp2[col], tp2b = Tp2[128 + col];

    float h[4];
    #pragma unroll
    for (int i = 0; i < 4; ++i) h[i] = h0[(size_t)(rb * 16 + g * 4 + i) * 128 + col];

    const size_t TSTR = 32 * 2048;   // per-t stride in elements
    const float* xcd_b = xcd + (size_t)rb * 2048;
    const float* kip_b = kipre + (size_t)rb * 2048;
    const unsigned short* xf_b = xfrag + (size_t)rb * 2048;

    f32x4 xc = *(const f32x4*)(xcd_b + (size_t)tid * 4);
    f32x4 xn = *(const f32x4*)(xcd_b + TSTR + (size_t)tid * 4);
    f32x4 kip = *(const f32x4*)(kip_b + (size_t)tid * 4);
    bf16x8 xf[4];
    #pragma unroll
    for (int kt = 0; kt < 4; ++kt) xf[kt] = *(const bf16x8*)(xf_b + ((size_t)kt * 64 + l) * 8);
    unsigned char cpk = cpkg[(size_t)(rb * 4 + g) * SS];

    #pragma unroll 1
    for (int t = 0; t < TT; ++t) {
        // ---- prefetch t+1 operands (consumed next iteration) ----
        int tn = t + 1;
        bf16x8 xfN[4];
        #pragma unroll
        for (int kt = 0; kt < 4; ++kt)
            xfN[kt] = *(const bf16x8*)(xf_b + (size_t)tn * TSTR + ((size_t)kt * 64 + l) * 8);
        int t2 = (t + 2 <= 499) ? t + 2 : 499;
        f32x4 xnN = *(const f32x4*)(xcd_b + (size_t)t2 * TSTR + (size_t)tid * 4);
        int tk = (tn <= 498) ? tn : 498;
        f32x4 kipN = *(const f32x4*)(kip_b + (size_t)tk * TSTR + (size_t)tid * 4);
        unsigned char cpkN = cpkg[(size_t)(rb * 4 + g) * SS + tk];

        // ---- phase 0: d = x_t - h, write bf16 to LDS (XOR-swizzled) ----
        #pragma unroll
        for (int i = 0; i < 4; ++i) {
            int row = g * 4 + i;
            int off = ((row * 256 + col * 2) ^ ((row & 7) << 4));
            *(unsigned short*)((char*)dbuf + off) = f2bf(xc[i] - h[i]);
        }
        __syncthreads();

        // ---- phase 1: s1,s2 = d@Wsdf1/2 ; gate = (x@Wki - d@Wki) + kipre ----
        f32x4 s1 = {0.f,0.f,0.f,0.f}, s2 = {0.f,0.f,0.f,0.f};
        f32x4 gx = {0.f,0.f,0.f,0.f}, gd = {0.f,0.f,0.f,0.f};
        #pragma unroll
        for (int kt = 0; kt < 4; ++kt) {
            int kb = kt * 32 + g * 8;
            int off = ((cl * 256 + kb * 2) ^ ((cl & 7) << 4));
            bf16x8 df = *(const bf16x8*)((char*)dbuf + off);
            s1 = __builtin_amdgcn_mfma_f32_16x16x32_bf16(df, wf[0][kt], s1, 0, 0, 0);
            s2 = __builtin_amdgcn_mfma_f32_16x16x32_bf16(df, wf[1][kt], s2, 0, 0, 0);
            gd = __builtin_amdgcn_mfma_f32_16x16x32_bf16(df, wf[4][kt], gd, 0, 0, 0);
            gx = __builtin_amdgcn_mfma_f32_16x16x32_bf16(xf[kt], wf[4][kt], gx, 0, 0, 0);
        }
        float gv[4];
        #pragma unroll
        for (int i = 0; i < 4; ++i) {
            float sdfv = fsig(s1[i] + bs1) * ftanh(s2[i] + bs2);
            gv[i] = fsig(gx[i] - gd[i] + kip[i]);
            int row = g * 4 + i;
            int off = ((row * 256 + col * 2) ^ ((row & 7) << 4));
            *(unsigned short*)((char*)sbuf + off) = f2bf(sdfv);
        }
        __syncthreads();

        // ---- phase 2: p1,p2 = sdf@Wpka1/2 ; h update ; y partial ----
        f32x4 p1 = {0.f,0.f,0.f,0.f}, p2 = {0.f,0.f,0.f,0.f};
        #pragma unroll
        for (int kt = 0; kt < 4; ++kt) {
            int kb = kt * 32 + g * 8;
            int off = ((cl * 256 + kb * 2) ^ ((cl & 7) << 4));
            bf16x8 sf = *(const bf16x8*)((char*)sbuf + off);
            p1 = __builtin_amdgcn_mfma_f32_16x16x32_bf16(sf, wf[2][kt], p1, 0, 0, 0);
            p2 = __builtin_amdgcn_mfma_f32_16x16x32_bf16(sf, wf[3][kt], p2, 0, 0, 0);
        }
        float yp[4];
        #pragma unroll
        for (int i = 0; i < 4; ++i) {
            float t1v = ((cpk >> i) & 1) ? tp1b : tp1a;
            float t2v = ((cpk >> i) & 1) ? tp2b : tp2a;
            float pka = fsig(p1[i] + t1v) * ftanh(p2[i] + t2v);
            h[i] = gv[i] * h[i] + (1.0f - gv[i]) * pka;
            yp[i] = xn[i] * h[i];
        }
        // reduce over 4 adjacent cols (2 xor-shuffles); K3 sums the remaining 8w x 4q
        #pragma unroll
        for (int i = 0; i < 4; ++i) { yp[i] += __shfl_xor(yp[i], 1); yp[i] += __shfl_xor(yp[i], 2); }
        if ((cl & 3) == 0) {
            size_t yb = (((size_t)t * 32 + rb) * 8 + w) * 64;
            int q = cl >> 2;
            #pragma unroll
            for (int i = 0; i < 4; ++i) ypart[yb + (size_t)(g * 4 + i) * 4 + q] = yp[i];
        }
        // rotate prefetched operands
        xc = xn; xn = xnN; kip = kipN; cpk = cpkN;
        #pragma unroll
        for (int kt = 0; kt < 4; ++kt) xf[kt] = xfN[kt];
    }
}

// ---------------- final: y[b][t] = sigmoid(sum of 32 partials); y[:,499] = 0 ----------------
__global__ __launch_bounds__(256) void k_yfinal(const float* __restrict__ ypart, float* __restrict__ y)
{
    int id = blockIdx.x * 256 + threadIdx.x;
    if (id >= BB * SS) return;
    int b = id / SS, t = id - b * SS;
    if (t == TT) { y[id] = 0.0f; return; }
    int rb = b >> 4, row = b & 15;
    float s = 0.0f;
    #pragma unroll
    for (int w = 0; w < 8; ++w) {
        f32x4 v = *(const f32x4*)&ypart[(((size_t)t * 32 + rb) * 8 + w) * 64 + (size_t)row * 4];
        s += v[0] + v[1] + v[2] + v[3];
    }
    y[id] = fsig(s);
}

// ---------------- launch ----------------
extern "C" void kernel_launch(void* const* d_in, const int* in_sizes, int n_in,
                              void* d_out, int out_size, void* d_ws, size_t ws_size,
                              hipStream_t stream) {
    const int* qs    = (const int*)d_in[0];
    const int* cs    = (const int*)d_in[1];
    const int* qds   = (const int*)d_in[2];
    const int* cds   = (const int*)d_in[3];
    const int* corr  = (const int*)d_in[4];
    const float* Eq    = (const float*)d_in[5];
    const float* Ec    = (const float*)d_in[6];
    const float* Eqd   = (const float*)d_in[7];
    const float* Ecd   = (const float*)d_in[8];
    const float* Ecorr = (const float*)d_in[9];
    const float* Wx    = (const float*)d_in[10];
    const float* bx    = (const float*)d_in[11];
    const float* Wsdf1 = (const float*)d_in[12];
    const float* bsdf1 = (const float*)d_in[13];
    const float* Wsdf2 = (const float*)d_in[14];
    const float* bsdf2 = (const float*)d_in[15];
    const float* Wpka1 = (const float*)d_in[16];
    const float* bpka1 = (const float*)d_in[17];
    const float* Wpka2 = (const float*)d_in[18];
    const float* bpka2 = (const float*)d_in[19];
    const float* Wki   = (const float*)d_in[20];
    const float* bki   = (const float*)d_in[21];
    const float* h0    = (const float*)d_in[22];

    char* base;
    if (ws_size >= TOTAL_WS) {
        base = (char*)d_ws;
    } else {
        void* p = nullptr;
        hipGetSymbolAddress(&p, HIP_SYMBOL(g_fb));
        base = (char*)p;
    }

    float* Txq   = (float*)(base + OFF_TXQ);
    float* Txc   = (float*)(base + OFF_TXC);
    float* Txqd  = (float*)(base + OFF_TXQD);
    float* Txcd  = (float*)(base + OFF_TXCD);
    float* TkiQd = (float*)(base + OFF_TKIQD);
    float* TkiCd = (float*)(base + OFF_TKICD);
    float* TkiCo = (float*)(base + OFF_TKICO);
    float* Tp1   = (float*)(base + OFF_TP1);
    float* Tp2   = (float*)(base + OFF_TP2);
    unsigned short* wfrag = (unsigned short*)(base + OFF_WFRAG);
    unsigned char*  cpk   = (unsigned char*)(base + OFF_CPK);
    float* xcd   = (float*)(base + OFF_XCD);
    unsigned short* xfrag = (unsigned short*)(base + OFF_XFRAG);
    float* kipre = (float*)(base + OFF_KIPRE);
    float* ypart = (float*)(base + OFF_YPART);

    k_tables<<<10906, 128, 0, stream>>>(Eq, Ec, Eqd, Ecd, Ecorr, Wx, bx,
                                        Wpka1, bpka1, Wpka2, bpka2, Wki, bki,
                                        Txq, Txc, Txqd, Txcd, TkiQd, TkiCd, TkiCo, Tp1, Tp2);
    k_wfrag<<<160, 64, 0, stream>>>(Wsdf1, Wsdf2, Wpka1, Wpka2, Wki, wfrag);
    k_gather<<<SS * NRB, 512, 0, stream>>>(qs, cs, qds, cds, corr,
                                           Txq, Txc, Txqd, Txcd, TkiQd, TkiCd, TkiCo,
                                           xcd, xfrag, kipre, cpk);
    k_rec<<<NRB, 512, 0, stream>>>(xcd, xfrag, kipre, cpk, wfrag, Tp1, Tp2,
                                   bsdf1, bsdf2, h0, ypart);
    k_yfinal<<<(BB * SS + 255) / 256, 256, 0, stream>>>(ypart, (float*)d_out);
}

// Round 2
// 980.167 us; speedup vs baseline: 1.4583x; 1.4583x over previous
//
#include <hip/hip_runtime.h>
#include <hip/hip_bf16.h>
#include <cstdint>
#include <cstddef>

// ---------------- problem constants ----------------
#define BB 512
#define SS 500
#define DD 128
#define TT 499            // scan steps t = 0..498
#define NRB 32            // recurrence blocks (16 rows each)

typedef float  f32x4  __attribute__((ext_vector_type(4)));
typedef short  bf16x8 __attribute__((ext_vector_type(8)));
typedef unsigned short ushort4v __attribute__((ext_vector_type(4)));

// ---------------- workspace layout (bytes) ----------------
static constexpr size_t OFF_TXQ   = 0;                 // 10000*128*4
static constexpr size_t OFF_TXC   = 5120000;           // 500*128*4
static constexpr size_t OFF_TXQD  = 5376000;           // 100*128*4
static constexpr size_t OFF_TXCD  = 5427200;           // 100*128*4
static constexpr size_t OFF_TKIQD = 5478400;           // 100*128*4 (+= Txqd@Wki0)
static constexpr size_t OFF_TKICD = 5529600;           // 100*128*4 (+= Txcd@Wki0)
static constexpr size_t OFF_TKICO = 5580800;           // 2*128*4 (pad 1024)
static constexpr size_t OFF_TP1   = 5581824;           // 2*128*4 (pad 1024)
static constexpr size_t OFF_TP2   = 5582848;           // 2*128*4 (pad 1024)
static constexpr size_t OFF_TXQ2  = 5583872;           // 10000*128*4 (Txq@Wki0)
static constexpr size_t OFF_TXC2  = 10703872;          // 500*128*4   (Txc@Wki0)
static constexpr size_t OFF_WFRAG = 10959872;          // 5*128*128*2
static constexpr size_t OFF_CPK   = 11123712;          // 32*4*500 (pad)
static constexpr size_t OFF_XCD   = 11188224;          // 500*32*2048*4
static constexpr size_t OFF_KIPRE = 142260224;         // 500*32*2048*4
static constexpr size_t OFF_YPART = 273332224;         // 499*32*8*64*4
static constexpr size_t TOTAL_WS  = 306034688;

// fallback scratch if harness workspace is too small
__device__ unsigned char g_fb[TOTAL_WS];

// ---------------- helpers ----------------
__device__ __forceinline__ unsigned short f2bf(float f) {
    union { float f; uint32_t u; } v; v.f = f;
    uint32_t u = v.u;
    uint32_t r = u + 0x7FFFu + ((u >> 16) & 1u);
    return (unsigned short)(r >> 16);
}
__device__ __forceinline__ float fsig(float z) {
    // 1/(1+exp(-z)) with hardware rcp (no IEEE divide)
    return __builtin_amdgcn_rcpf(1.0f + __expf(-z));
}
__device__ __forceinline__ float sigtanh(float a, float b) {
    // sigmoid(a) * tanh(b) with a single rcp:
    // = (1 - e^{-2b}) / ((1 + e^{-a}) (1 + e^{-2b}))
    float e1 = __expf(-a);
    float e2 = __expf(-2.0f * b);
    return (1.0f - e2) * __builtin_amdgcn_rcpf((1.0f + e1) * (1.0f + e2));
}
// barrier that only orders LDS traffic: do NOT drain vmcnt (prefetch stays in flight)
__device__ __forceinline__ void bar_lgkm() {
    asm volatile("s_waitcnt lgkmcnt(0)" ::: "memory");
    __builtin_amdgcn_s_barrier();
}

// ---------------- P1: per-table GEMM products ----------------
__global__ __launch_bounds__(128) void k_tables(
    const float* __restrict__ Eq, const float* __restrict__ Ec,
    const float* __restrict__ Eqd, const float* __restrict__ Ecd,
    const float* __restrict__ Ecorr,
    const float* __restrict__ Wx,  const float* __restrict__ bx,
    const float* __restrict__ Wpka1, const float* __restrict__ bpka1,
    const float* __restrict__ Wpka2, const float* __restrict__ bpka2,
    const float* __restrict__ Wki, const float* __restrict__ bki,
    float* __restrict__ Txq, float* __restrict__ Txc,
    float* __restrict__ Txqd, float* __restrict__ Txcd,
    float* __restrict__ TkiQd, float* __restrict__ TkiCd, float* __restrict__ TkiCo,
    float* __restrict__ Tp1, float* __restrict__ Tp2)
{
    int blk = blockIdx.x;
    const float* A; const float* W; const float* bias = nullptr; float* out; int row;
    if      (blk < 10000) { A = Eq;    row = blk;          W = Wx;              bias = bx;    out = Txq;  }
    else if (blk < 10500) { A = Ec;    row = blk - 10000;  W = Wx  + 128*128;                 out = Txc;  }
    else if (blk < 10600) { A = Eqd;   row = blk - 10500;  W = Wx  + 256*128;                 out = Txqd; }
    else if (blk < 10700) { A = Ecd;   row = blk - 10600;  W = Wx  + 384*128;                 out = Txcd; }
    else if (blk < 10800) { A = Eqd;   row = blk - 10700;  W = Wki + 256*128;                 out = TkiQd;}
    else if (blk < 10900) { A = Ecd;   row = blk - 10800;  W = Wki + 384*128;                 out = TkiCd;}
    else if (blk < 10902) { A = Ecorr; row = blk - 10900;  W = Wki + 128*128;   bias = bki;   out = TkiCo;}
    else if (blk < 10904) { A = Ecorr; row = blk - 10902;  W = Wpka1 + 128*128; bias = bpka1; out = Tp1;  }
    else                  { A = Ecorr; row = blk - 10904;  W = Wpka2 + 128*128; bias = bpka2; out = Tp2;  }

    __shared__ float a[128];
    int c = threadIdx.x;
    a[c] = A[row * 128 + c];
    __syncthreads();
    float acc = bias ? bias[c] : 0.0f;
    #pragma unroll 8
    for (int k = 0; k < 128; ++k) acc += a[k] * W[k * 128 + c];
    out[row * 128 + c] = acc;
}

// ---------------- P1b: fold x@Wki0 into tables (x is h-independent part of the gate) ----
// Txq2 = Txq@Wki0 ; Txc2 = Txc@Wki0 ; TkiQd += Txqd@Wki0 ; TkiCd += Txcd@Wki0
__global__ __launch_bounds__(128) void k_tables2(
    const float* __restrict__ Wki,
    const float* __restrict__ Txq, const float* __restrict__ Txc,
    const float* __restrict__ Txqd, const float* __restrict__ Txcd,
    float* __restrict__ Txq2, float* __restrict__ Txc2,
    float* __restrict__ TkiQd, float* __restrict__ TkiCd)
{
    int blk = blockIdx.x;
    const float* A; float* out; int row; bool accum;
    if      (blk < 10000) { A = Txq;  row = blk;          out = Txq2;  accum = false; }
    else if (blk < 10500) { A = Txc;  row = blk - 10000;  out = Txc2;  accum = false; }
    else if (blk < 10600) { A = Txqd; row = blk - 10500;  out = TkiQd; accum = true;  }
    else                  { A = Txcd; row = blk - 10600;  out = TkiCd; accum = true;  }
    __shared__ float a[128];
    int c = threadIdx.x;
    a[c] = A[row * 128 + c];
    __syncthreads();
    float acc = accum ? out[row * 128 + c] : 0.0f;
    #pragma unroll 8
    for (int k = 0; k < 128; ++k) acc += a[k] * Wki[k * 128 + c];
    out[row * 128 + c] = acc;
}

// ---------------- P0: weight matrices -> MFMA B-fragments (bf16) ----------------
__global__ __launch_bounds__(64) void k_wfrag(
    const float* __restrict__ Wsdf1, const float* __restrict__ Wsdf2,
    const float* __restrict__ Wpka1, const float* __restrict__ Wpka2,
    const float* __restrict__ Wki, unsigned short* __restrict__ wfrag)
{
    int bid = blockIdx.x;                 // 5 * 8 * 4 = 160
    int m = bid >> 5, w = (bid >> 2) & 7, kt = bid & 3;
    const float* W = (m == 0) ? Wsdf1 : (m == 1) ? Wsdf2 : (m == 2) ? Wpka1 : (m == 3) ? Wpka2 : Wki;
    int l = threadIdx.x;
    int cc = w * 16 + (l & 15);
    int k0 = kt * 32 + ((l >> 4) << 3);
    unsigned short v[8];
    #pragma unroll
    for (int j = 0; j < 8; ++j) v[j] = f2bf(W[(size_t)(k0 + j) * 128 + cc]);
    unsigned short* dst = wfrag + ((( (size_t)m * 8 + w) * 4 + kt) * 64 + l) * 8;
    #pragma unroll
    for (int j = 0; j < 8; ++j) dst[j] = v[j];
}

// ---------------- P2: materialize x / kipre in recurrence layouts ----------------
__global__ __launch_bounds__(512) void k_gather(
    const int* __restrict__ qs, const int* __restrict__ cs,
    const int* __restrict__ qds, const int* __restrict__ cds, const int* __restrict__ corr,
    const float* __restrict__ Txq, const float* __restrict__ Txc,
    const float* __restrict__ Txqd, const float* __restrict__ Txcd,
    const float* __restrict__ Txq2, const float* __restrict__ Txc2,
    const float* __restrict__ TkiQd, const float* __restrict__ TkiCd, const float* __restrict__ TkiCo,
    float* __restrict__ xcd, float* __restrict__ kipre, unsigned char* __restrict__ cpk)
{
    int bid = blockIdx.x;
    int t = bid >> 5, rb = bid & 31;
    __shared__ float xl[16][128];
    __shared__ float kl[16][128];
    __shared__ int idx[5][16];
    int tid = threadIdx.x;
    if (tid < 80) {
        int which = tid >> 4, row = tid & 15;
        const int* P = (which == 0) ? qs : (which == 1) ? cs : (which == 2) ? qds : (which == 3) ? cds : corr;
        idx[which][row] = P[(size_t)(rb * 16 + row) * SS + t];
    }
    __syncthreads();
    {
        int row = tid >> 5; int c0 = (tid & 31) * 4;
        f32x4 xq = *(const f32x4*)&Txq [(size_t)idx[0][row] * 128 + c0];
        f32x4 xc = *(const f32x4*)&Txc [(size_t)idx[1][row] * 128 + c0];
        f32x4 xd = *(const f32x4*)&Txqd[(size_t)idx[2][row] * 128 + c0];
        f32x4 xe = *(const f32x4*)&Txcd[(size_t)idx[3][row] * 128 + c0];
        f32x4 k0 = *(const f32x4*)&Txq2[(size_t)idx[0][row] * 128 + c0];
        f32x4 k4 = *(const f32x4*)&Txc2[(size_t)idx[1][row] * 128 + c0];
        f32x4 k1 = *(const f32x4*)&TkiQd[(size_t)idx[2][row] * 128 + c0];
        f32x4 k2 = *(const f32x4*)&TkiCd[(size_t)idx[3][row] * 128 + c0];
        f32x4 k3 = *(const f32x4*)&TkiCo[(size_t)idx[4][row] * 128 + c0];
        #pragma unroll
        for (int i = 0; i < 4; ++i) {
            xl[row][c0 + i] = xq[i] + xc[i] + xd[i] + xe[i];
            kl[row][c0 + i] = k0[i] + k4[i] + k1[i] + k2[i] + k3[i];
        }
    }
    __syncthreads();
    size_t base = (size_t)bid * 2048;
    {   // C/D-layout f32 copies: element (w,l,i) = x[(l>>4)*4+i][w*16+(l&15)]
        int w = tid >> 6, l = tid & 63;
        int g = l >> 4, cc = w * 16 + (l & 15);
        f32x4 o, o2;
        #pragma unroll
        for (int i = 0; i < 4; ++i) { o[i] = xl[g * 4 + i][cc]; o2[i] = kl[g * 4 + i][cc]; }
        *(f32x4*)&xcd[base + (size_t)tid * 4]   = o;
        *(f32x4*)&kipre[base + (size_t)tid * 4] = o2;
    }
    if (tid < 4) {  // packed correct-bits
        unsigned char b = 0;
        #pragma unroll
        for (int i = 0; i < 4; ++i) b |= (unsigned char)((idx[4][tid * 4 + i] & 1) << i);
        cpk[(size_t)(rb * 4 + tid) * SS + t] = b;
    }
}

// ---------------- recurrence: 32 blocks x 512 threads (8 waves x 16-col slices) ----------------
__global__ __launch_bounds__(512, 2) void k_rec(
    const float* __restrict__ xcd, const float* __restrict__ kipre,
    const unsigned char* __restrict__ cpkg,
    const unsigned short* __restrict__ wfrag,
    const float* __restrict__ Tp1, const float* __restrict__ Tp2,
    const float* __restrict__ bsdf1, const float* __restrict__ bsdf2,
    const float* __restrict__ h0, float* __restrict__ ypart)
{
    int rb = blockIdx.x;
    int tid = threadIdx.x;
    int w = tid >> 6, l = tid & 63;
    int g = l >> 4, cl = l & 15;
    int col = w * 16 + cl;

    __shared__ __align__(16) unsigned short dbuf[2048];
    __shared__ __align__(16) unsigned short sbuf[2048];

    // weight B-fragments (5 matrices x 4 k-tiles); m4 = Wki rows 0..127
    bf16x8 wf[5][4];
    #pragma unroll
    for (int m = 0; m < 5; ++m)
        #pragma unroll
        for (int kt = 0; kt < 4; ++kt)
            wf[m][kt] = *(const bf16x8*)(wfrag + ((((size_t)m * 8 + w) * 4 + kt) * 64 + l) * 8);

    float bs1 = bsdf1[col], bs2 = bsdf2[col];
    float tp1a = Tp1[col], tp1b = Tp1[128 + col];
    float tp2a = Tp2[col], tp2b = Tp2[128 + col];

    float h[4];
    #pragma unroll
    for (int i = 0; i < 4; ++i) h[i] = h0[(size_t)(rb * 16 + g * 4 + i) * 128 + col];

    // hoisted LDS byte offsets (XOR-swizzled)
    int offW[4], offR[4];
    #pragma unroll
    for (int i = 0; i < 4; ++i) {
        int row = g * 4 + i;
        offW[i] = ((row * 256 + col * 2) ^ ((row & 7) << 4));
    }
    #pragma unroll
    for (int kt = 0; kt < 4; ++kt) {
        int kb = kt * 32 + g * 8;
        offR[kt] = ((cl * 256 + kb * 2) ^ ((cl & 7) << 4));
    }

    const size_t TSTR = 32 * 2048;   // per-t element stride (= 65536, a shift)
    const float* xcd_t = xcd + (size_t)rb * 2048 + (size_t)tid * 4;
    const float* kip_t = kipre + (size_t)rb * 2048 + (size_t)tid * 4;
    const unsigned char* cp = cpkg + (size_t)(rb * 4 + g) * SS;

    f32x4 xc = *(const f32x4*)(xcd_t);
    f32x4 xn = *(const f32x4*)(xcd_t + TSTR);
    f32x4 kip = *(const f32x4*)(kip_t);
    unsigned char cpk = cp[0];

    #pragma unroll 1
    for (int t = 0; t < TT; ++t) {
        // ---- prefetch (consumed next iteration; vmcnt NOT drained at barriers) ----
        int t2 = (t + 2 <= 499) ? t + 2 : 499;
        int tk = (t + 1 <= 499) ? t + 1 : 499;
        int tc = (t + 1 <= 498) ? t + 1 : 498;
        f32x4 xnN  = *(const f32x4*)(xcd_t + (size_t)t2 * TSTR);
        f32x4 kipN = *(const f32x4*)(kip_t + (size_t)tk * TSTR);
        unsigned char cpkN = cp[tc];

        // ---- phase 0: d = x_t - h -> LDS (bf16, swizzled) ----
        #pragma unroll
        for (int i = 0; i < 4; ++i)
            *(unsigned short*)((char*)dbuf + offW[i]) = f2bf(xc[i] - h[i]);
        bar_lgkm();

        // ---- phase 1: s1,s2 = d@Wsdf1/2 ; gd = d@Wki0 ----
        f32x4 s1 = {0.f,0.f,0.f,0.f}, s2 = {0.f,0.f,0.f,0.f}, gd = {0.f,0.f,0.f,0.f};
        #pragma unroll
        for (int kt = 0; kt < 4; ++kt) {
            bf16x8 df = *(const bf16x8*)((char*)dbuf + offR[kt]);
            s1 = __builtin_amdgcn_mfma_f32_16x16x32_bf16(df, wf[0][kt], s1, 0, 0, 0);
            s2 = __builtin_amdgcn_mfma_f32_16x16x32_bf16(df, wf[1][kt], s2, 0, 0, 0);
            gd = __builtin_amdgcn_mfma_f32_16x16x32_bf16(df, wf[4][kt], gd, 0, 0, 0);
        }
        float gv[4];
        #pragma unroll
        for (int i = 0; i < 4; ++i) {
            float sdfv = sigtanh(s1[i] + bs1, s2[i] + bs2);
            gv[i] = fsig(kip[i] - gd[i]);           // gate = sig(x@Wki0 - d@Wki0 + rest)
            *(unsigned short*)((char*)sbuf + offW[i]) = f2bf(sdfv);
        }
        bar_lgkm();

        // ---- phase 2: p1,p2 = sdf@Wpka1/2 ; h update ; y partial ----
        f32x4 p1 = {0.f,0.f,0.f,0.f}, p2 = {0.f,0.f,0.f,0.f};
        #pragma unroll
        for (int kt = 0; kt < 4; ++kt) {
            bf16x8 sf = *(const bf16x8*)((char*)sbuf + offR[kt]);
            p1 = __builtin_amdgcn_mfma_f32_16x16x32_bf16(sf, wf[2][kt], p1, 0, 0, 0);
            p2 = __builtin_amdgcn_mfma_f32_16x16x32_bf16(sf, wf[3][kt], p2, 0, 0, 0);
        }
        float yp[4];
        #pragma unroll
        for (int i = 0; i < 4; ++i) {
            float t1v = ((cpk >> i) & 1) ? tp1b : tp1a;
            float t2v = ((cpk >> i) & 1) ? tp2b : tp2a;
            float pka = sigtanh(p1[i] + t1v, p2[i] + t2v);
            h[i] = gv[i] * h[i] + (1.0f - gv[i]) * pka;
            yp[i] = xn[i] * h[i];
        }
        #pragma unroll
        for (int i = 0; i < 4; ++i) { yp[i] += __shfl_xor(yp[i], 1); yp[i] += __shfl_xor(yp[i], 2); }
        if ((cl & 3) == 0) {
            size_t yb = (((size_t)t * 32 + rb) * 8 + w) * 64;
            int q = cl >> 2;
            #pragma unroll
            for (int i = 0; i < 4; ++i) ypart[yb + (size_t)(g * 4 + i) * 4 + q] = yp[i];
        }
        // rotate prefetched operands
        xc = xn; xn = xnN; kip = kipN; cpk = cpkN;
    }
}

// ---------------- final: y[b][t] = sigmoid(sum of 32 partials); y[:,499] = 0 ----------------
__global__ __launch_bounds__(256) void k_yfinal(const float* __restrict__ ypart, float* __restrict__ y)
{
    int id = blockIdx.x * 256 + threadIdx.x;
    if (id >= BB * SS) return;
    int b = id / SS, t = id - b * SS;
    if (t == TT) { y[id] = 0.0f; return; }
    int rb = b >> 4, row = b & 15;
    float s = 0.0f;
    #pragma unroll
    for (int w = 0; w < 8; ++w) {
        f32x4 v = *(const f32x4*)&ypart[(((size_t)t * 32 + rb) * 8 + w) * 64 + (size_t)row * 4];
        s += v[0] + v[1] + v[2] + v[3];
    }
    y[id] = fsig(s);
}

// ---------------- launch ----------------
extern "C" void kernel_launch(void* const* d_in, const int* in_sizes, int n_in,
                              void* d_out, int out_size, void* d_ws, size_t ws_size,
                              hipStream_t stream) {
    const int* qs    = (const int*)d_in[0];
    const int* cs    = (const int*)d_in[1];
    const int* qds   = (const int*)d_in[2];
    const int* cds   = (const int*)d_in[3];
    const int* corr  = (const int*)d_in[4];
    const float* Eq    = (const float*)d_in[5];
    const float* Ec    = (const float*)d_in[6];
    const float* Eqd   = (const float*)d_in[7];
    const float* Ecd   = (const float*)d_in[8];
    const float* Ecorr = (const float*)d_in[9];
    const float* Wx    = (const float*)d_in[10];
    const float* bx    = (const float*)d_in[11];
    const float* Wsdf1 = (const float*)d_in[12];
    const float* bsdf1 = (const float*)d_in[13];
    const float* Wsdf2 = (const float*)d_in[14];
    const float* bsdf2 = (const float*)d_in[15];
    const float* Wpka1 = (const float*)d_in[16];
    const float* bpka1 = (const float*)d_in[17];
    const float* Wpka2 = (const float*)d_in[18];
    const float* bpka2 = (const float*)d_in[19];
    const float* Wki   = (const float*)d_in[20];
    const float* bki   = (const float*)d_in[21];
    const float* h0    = (const float*)d_in[22];

    char* base;
    if (ws_size >= TOTAL_WS) {
        base = (char*)d_ws;
    } else {
        void* p = nullptr;
        hipGetSymbolAddress(&p, HIP_SYMBOL(g_fb));
        base = (char*)p;
    }

    float* Txq   = (float*)(base + OFF_TXQ);
    float* Txc   = (float*)(base + OFF_TXC);
    float* Txqd  = (float*)(base + OFF_TXQD);
    float* Txcd  = (float*)(base + OFF_TXCD);
    float* TkiQd = (float*)(base + OFF_TKIQD);
    float* TkiCd = (float*)(base + OFF_TKICD);
    float* TkiCo = (float*)(base + OFF_TKICO);
    float* Tp1   = (float*)(base + OFF_TP1);
    float* Tp2   = (float*)(base + OFF_TP2);
    float* Txq2  = (float*)(base + OFF_TXQ2);
    float* Txc2  = (float*)(base + OFF_TXC2);
    unsigned short* wfrag = (unsigned short*)(base + OFF_WFRAG);
    unsigned char*  cpk   = (unsigned char*)(base + OFF_CPK);
    float* xcd   = (float*)(base + OFF_XCD);
    float* kipre = (float*)(base + OFF_KIPRE);
    float* ypart = (float*)(base + OFF_YPART);

    k_tables<<<10906, 128, 0, stream>>>(Eq, Ec, Eqd, Ecd, Ecorr, Wx, bx,
                                        Wpka1, bpka1, Wpka2, bpka2, Wki, bki,
                                        Txq, Txc, Txqd, Txcd, TkiQd, TkiCd, TkiCo, Tp1, Tp2);
    k_tables2<<<10700, 128, 0, stream>>>(Wki, Txq, Txc, Txqd, Txcd, Txq2, Txc2, TkiQd, TkiCd);
    k_wfrag<<<160, 64, 0, stream>>>(Wsdf1, Wsdf2, Wpka1, Wpka2, Wki, wfrag);
    k_gather<<<SS * NRB, 512, 0, stream>>>(qs, cs, qds, cds, corr,
                                           Txq, Txc, Txqd, Txcd, Txq2, Txc2,
                                           TkiQd, TkiCd, TkiCo, xcd, kipre, cpk);
    k_rec<<<NRB, 512, 0, stream>>>(xcd, kipre, cpk, wfrag, Tp1, Tp2,
                                   bsdf1, bsdf2, h0, ypart);
    k_yfinal<<<(BB * SS + 255) / 256, 256, 0, stream>>>(ypart, (float*)d_out);
}

// Round 3
// 828.177 us; speedup vs baseline: 1.7260x; 1.1835x over previous
//
#include <hip/hip_runtime.h>
#include <hip/hip_bf16.h>
#include <cstdint>
#include <cstddef>

// ---------------- problem constants ----------------
#define BB 512
#define SS 500
#define DD 128
#define TT 499            // scan steps t = 0..498
#define NRB 32            // recurrence blocks (16 rows each)

typedef float  f32x4  __attribute__((ext_vector_type(4)));
typedef short  bf16x8 __attribute__((ext_vector_type(8)));

// ---------------- workspace layout (bytes) ----------------
static constexpr size_t OFF_TXQ   = 0;                 // 10000*128*4
static constexpr size_t OFF_TXC   = 5120000;           // 500*128*4
static constexpr size_t OFF_TXQD  = 5376000;           // 100*128*4
static constexpr size_t OFF_TXCD  = 5427200;           // 100*128*4
static constexpr size_t OFF_TKIQD = 5478400;           // 100*128*4 (+= Txqd@Wki0)
static constexpr size_t OFF_TKICD = 5529600;           // 100*128*4 (+= Txcd@Wki0)
static constexpr size_t OFF_TKICO = 5580800;           // 2*128*4 (pad 1024)
static constexpr size_t OFF_TP1   = 5581824;           // 2*128*4 (pad 1024)
static constexpr size_t OFF_TP2   = 5582848;           // 2*128*4 (pad 1024)
static constexpr size_t OFF_TXQ2  = 5583872;           // 10000*128*4 (Txq@Wki0)
static constexpr size_t OFF_TXC2  = 10703872;          // 500*128*4   (Txc@Wki0)
static constexpr size_t OFF_WFRAG = 10959872;          // 5*128*128*2
static constexpr size_t OFF_CPK   = 11123712;          // 32*4*500 (pad)
static constexpr size_t OFF_XCD   = 11188224;          // 500*32*2048*4
static constexpr size_t OFF_KIPRE = 142260224;         // 500*32*2048*4
static constexpr size_t OFF_YPART = 273332224;         // 499*32*8*64*4
static constexpr size_t TOTAL_WS  = 306034688;

// fallback scratch if harness workspace is too small
__device__ unsigned char g_fb[TOTAL_WS];

// ---------------- helpers ----------------
__device__ __forceinline__ unsigned short f2bf(float f) {
    union { float f; uint32_t u; } v; v.f = f;
    uint32_t u = v.u;
    uint32_t r = u + 0x7FFFu + ((u >> 16) & 1u);
    return (unsigned short)(r >> 16);
}
__device__ __forceinline__ float fsig(float z) {
    return __builtin_amdgcn_rcpf(1.0f + __expf(-z));
}
__device__ __forceinline__ float sigtanh(float a, float b) {
    // sigmoid(a) * tanh(b) with a single rcp
    float e1 = __expf(-a);
    float e2 = __expf(-2.0f * b);
    return (1.0f - e2) * __builtin_amdgcn_rcpf((1.0f + e1) * (1.0f + e2));
}
// barrier that only orders LDS traffic: do NOT drain vmcnt (prefetch stays in flight)
__device__ __forceinline__ void bar_lgkm() {
    asm volatile("s_waitcnt lgkmcnt(0)" ::: "memory");
    __builtin_amdgcn_s_barrier();
}
// sum over aligned lane quads via DPP quad_perm (no LDS traffic)
__device__ __forceinline__ float quad_sum(float x) {
    int a = __float_as_int(x);
    int b = __builtin_amdgcn_update_dpp(a, a, 0xB1, 0xF, 0xF, false); // xor 1
    float s = x + __int_as_float(b);
    int c = __float_as_int(s);
    int d = __builtin_amdgcn_update_dpp(c, c, 0x4E, 0xF, 0xF, false); // xor 2
    return s + __int_as_float(d);
}

// ---------------- P1: per-table GEMM products ----------------
__global__ __launch_bounds__(128) void k_tables(
    const float* __restrict__ Eq, const float* __restrict__ Ec,
    const float* __restrict__ Eqd, const float* __restrict__ Ecd,
    const float* __restrict__ Ecorr,
    const float* __restrict__ Wx,  const float* __restrict__ bx,
    const float* __restrict__ Wpka1, const float* __restrict__ bpka1,
    const float* __restrict__ Wpka2, const float* __restrict__ bpka2,
    const float* __restrict__ Wki, const float* __restrict__ bki,
    float* __restrict__ Txq, float* __restrict__ Txc,
    float* __restrict__ Txqd, float* __restrict__ Txcd,
    float* __restrict__ TkiQd, float* __restrict__ TkiCd, float* __restrict__ TkiCo,
    float* __restrict__ Tp1, float* __restrict__ Tp2)
{
    int blk = blockIdx.x;
    const float* A; const float* W; const float* bias = nullptr; float* out; int row;
    if      (blk < 10000) { A = Eq;    row = blk;          W = Wx;              bias = bx;    out = Txq;  }
    else if (blk < 10500) { A = Ec;    row = blk - 10000;  W = Wx  + 128*128;                 out = Txc;  }
    else if (blk < 10600) { A = Eqd;   row = blk - 10500;  W = Wx  + 256*128;                 out = Txqd; }
    else if (blk < 10700) { A = Ecd;   row = blk - 10600;  W = Wx  + 384*128;                 out = Txcd; }
    else if (blk < 10800) { A = Eqd;   row = blk - 10700;  W = Wki + 256*128;                 out = TkiQd;}
    else if (blk < 10900) { A = Ecd;   row = blk - 10800;  W = Wki + 384*128;                 out = TkiCd;}
    else if (blk < 10902) { A = Ecorr; row = blk - 10900;  W = Wki + 128*128;   bias = bki;   out = TkiCo;}
    else if (blk < 10904) { A = Ecorr; row = blk - 10902;  W = Wpka1 + 128*128; bias = bpka1; out = Tp1;  }
    else                  { A = Ecorr; row = blk - 10904;  W = Wpka2 + 128*128; bias = bpka2; out = Tp2;  }

    __shared__ float a[128];
    int c = threadIdx.x;
    a[c] = A[row * 128 + c];
    __syncthreads();
    float acc = bias ? bias[c] : 0.0f;
    #pragma unroll 8
    for (int k = 0; k < 128; ++k) acc += a[k] * W[k * 128 + c];
    out[row * 128 + c] = acc;
}

// ---------------- P1b: fold x@Wki0 into tables ----------------
__global__ __launch_bounds__(128) void k_tables2(
    const float* __restrict__ Wki,
    const float* __restrict__ Txq, const float* __restrict__ Txc,
    const float* __restrict__ Txqd, const float* __restrict__ Txcd,
    float* __restrict__ Txq2, float* __restrict__ Txc2,
    float* __restrict__ TkiQd, float* __restrict__ TkiCd)
{
    int blk = blockIdx.x;
    const float* A; float* out; int row; bool accum;
    if      (blk < 10000) { A = Txq;  row = blk;          out = Txq2;  accum = false; }
    else if (blk < 10500) { A = Txc;  row = blk - 10000;  out = Txc2;  accum = false; }
    else if (blk < 10600) { A = Txqd; row = blk - 10500;  out = TkiQd; accum = true;  }
    else                  { A = Txcd; row = blk - 10600;  out = TkiCd; accum = true;  }
    __shared__ float a[128];
    int c = threadIdx.x;
    a[c] = A[row * 128 + c];
    __syncthreads();
    float acc = accum ? out[row * 128 + c] : 0.0f;
    #pragma unroll 8
    for (int k = 0; k < 128; ++k) acc += a[k] * Wki[k * 128 + c];
    out[row * 128 + c] = acc;
}

// ---------------- P0: weight matrices -> MFMA B-fragments (bf16) ----------------
// m=4 (Wki rows 0..127) is NEGATED so gate acc = kipre + d@(-Wki0) = kipre - d@Wki0
__global__ __launch_bounds__(64) void k_wfrag(
    const float* __restrict__ Wsdf1, const float* __restrict__ Wsdf2,
    const float* __restrict__ Wpka1, const float* __restrict__ Wpka2,
    const float* __restrict__ Wki, unsigned short* __restrict__ wfrag)
{
    int bid = blockIdx.x;                 // 5 * 8 * 4 = 160
    int m = bid >> 5, w = (bid >> 2) & 7, kt = bid & 3;
    const float* W = (m == 0) ? Wsdf1 : (m == 1) ? Wsdf2 : (m == 2) ? Wpka1 : (m == 3) ? Wpka2 : Wki;
    float sgn = (m == 4) ? -1.0f : 1.0f;
    int l = threadIdx.x;
    int cc = w * 16 + (l & 15);
    int k0 = kt * 32 + ((l >> 4) << 3);
    unsigned short v[8];
    #pragma unroll
    for (int j = 0; j < 8; ++j) v[j] = f2bf(sgn * W[(size_t)(k0 + j) * 128 + cc]);
    unsigned short* dst = wfrag + ((( (size_t)m * 8 + w) * 4 + kt) * 64 + l) * 8;
    #pragma unroll
    for (int j = 0; j < 8; ++j) dst[j] = v[j];
}

// ---------------- P2: materialize x / kipre in recurrence layouts ----------------
__global__ __launch_bounds__(512) void k_gather(
    const int* __restrict__ qs, const int* __restrict__ cs,
    const int* __restrict__ qds, const int* __restrict__ cds, const int* __restrict__ corr,
    const float* __restrict__ Txq, const float* __restrict__ Txc,
    const float* __restrict__ Txqd, const float* __restrict__ Txcd,
    const float* __restrict__ Txq2, const float* __restrict__ Txc2,
    const float* __restrict__ TkiQd, const float* __restrict__ TkiCd, const float* __restrict__ TkiCo,
    float* __restrict__ xcd, float* __restrict__ kipre, unsigned char* __restrict__ cpk)
{
    int bid = blockIdx.x;
    int t = bid >> 5, rb = bid & 31;
    __shared__ float xl[16][128];
    __shared__ float kl[16][128];
    __shared__ int idx[5][16];
    int tid = threadIdx.x;
    if (tid < 80) {
        int which = tid >> 4, row = tid & 15;
        const int* P = (which == 0) ? qs : (which == 1) ? cs : (which == 2) ? qds : (which == 3) ? cds : corr;
        idx[which][row] = P[(size_t)(rb * 16 + row) * SS + t];
    }
    __syncthreads();
    {
        int row = tid >> 5; int c0 = (tid & 31) * 4;
        f32x4 xq = *(const f32x4*)&Txq [(size_t)idx[0][row] * 128 + c0];
        f32x4 xc = *(const f32x4*)&Txc [(size_t)idx[1][row] * 128 + c0];
        f32x4 xd = *(const f32x4*)&Txqd[(size_t)idx[2][row] * 128 + c0];
        f32x4 xe = *(const f32x4*)&Txcd[(size_t)idx[3][row] * 128 + c0];
        f32x4 k0 = *(const f32x4*)&Txq2[(size_t)idx[0][row] * 128 + c0];
        f32x4 k4 = *(const f32x4*)&Txc2[(size_t)idx[1][row] * 128 + c0];
        f32x4 k1 = *(const f32x4*)&TkiQd[(size_t)idx[2][row] * 128 + c0];
        f32x4 k2 = *(const f32x4*)&TkiCd[(size_t)idx[3][row] * 128 + c0];
        f32x4 k3 = *(const f32x4*)&TkiCo[(size_t)idx[4][row] * 128 + c0];
        #pragma unroll
        for (int i = 0; i < 4; ++i) {
            xl[row][c0 + i] = xq[i] + xc[i] + xd[i] + xe[i];
            kl[row][c0 + i] = k0[i] + k4[i] + k1[i] + k2[i] + k3[i];
        }
    }
    __syncthreads();
    size_t base = (size_t)bid * 2048;
    {   // C/D-layout f32 copies: element (w,l,i) = x[(l>>4)*4+i][w*16+(l&15)]
        int w = tid >> 6, l = tid & 63;
        int g = l >> 4, cc = w * 16 + (l & 15);
        f32x4 o, o2;
        #pragma unroll
        for (int i = 0; i < 4; ++i) { o[i] = xl[g * 4 + i][cc]; o2[i] = kl[g * 4 + i][cc]; }
        *(f32x4*)&xcd[base + (size_t)tid * 4]   = o;
        *(f32x4*)&kipre[base + (size_t)tid * 4] = o2;
    }
    if (tid < 4) {  // packed correct-bits
        unsigned char b = 0;
        #pragma unroll
        for (int i = 0; i < 4; ++i) b |= (unsigned char)((idx[4][tid * 4 + i] & 1) << i);
        cpk[(size_t)(rb * 4 + tid) * SS + t] = b;
    }
}

// ---------------- recurrence: 32 blocks x 512 threads (8 waves x 16-col slices) ----------------
__global__ __launch_bounds__(512, 2) void k_rec(
    const float* __restrict__ xcd, const float* __restrict__ kipre,
    const unsigned char* __restrict__ cpkg,
    const unsigned short* __restrict__ wfrag,
    const float* __restrict__ Tp1, const float* __restrict__ Tp2,
    const float* __restrict__ bsdf1, const float* __restrict__ bsdf2,
    const float* __restrict__ h0, float* __restrict__ ypart)
{
    int rb = blockIdx.x;
    int tid = threadIdx.x;
    int w = tid >> 6, l = tid & 63;
    int g = l >> 4, cl = l & 15;
    int col = w * 16 + cl;

    __shared__ __align__(16) unsigned short dbuf[2048];
    __shared__ __align__(16) unsigned short sbuf[2048];

    // weight B-fragments (5 matrices x 4 k-tiles); m4 = -Wki rows 0..127
    bf16x8 wf[5][4];
    #pragma unroll
    for (int m = 0; m < 5; ++m)
        #pragma unroll
        for (int kt = 0; kt < 4; ++kt)
            wf[m][kt] = *(const bf16x8*)(wfrag + ((((size_t)m * 8 + w) * 4 + kt) * 64 + l) * 8);

    float bs1 = bsdf1[col], bs2 = bsdf2[col];
    float tp1a = Tp1[col], tp1b = Tp1[128 + col];
    float tp2a = Tp2[col], tp2b = Tp2[128 + col];

    float h[4];
    #pragma unroll
    for (int i = 0; i < 4; ++i) h[i] = h0[(size_t)(rb * 16 + g * 4 + i) * 128 + col];

    // hoisted LDS byte offsets; XOR swizzle uses row&15 (rows r, r+8 no longer alias banks)
    int offW[4], offR[4];
    #pragma unroll
    for (int i = 0; i < 4; ++i) {
        int row = g * 4 + i;
        offW[i] = ((row * 256 + col * 2) ^ ((row & 15) << 4));
    }
    #pragma unroll
    for (int kt = 0; kt < 4; ++kt) {
        offR[kt] = (cl * 256 + (((4 * kt + g) ^ cl) << 4));
    }

    const size_t TSTR = 32 * 2048;   // per-t element stride
    const float* xp = xcd + (size_t)rb * 2048 + (size_t)tid * 4;
    const float* kp = kipre + (size_t)rb * 2048 + (size_t)tid * 4;
    const unsigned char* cp = cpkg + (size_t)(rb * 4 + g) * SS;

    // prefetch pipeline (depth 2)
    f32x4 xn  = *(const f32x4*)(xp + TSTR);         // x(t+1)
    f32x4 xn2 = *(const f32x4*)(xp + 2 * TSTR);     // x(t+2)
    f32x4 kip  = *(const f32x4*)(kp);               // kipre(t)
    f32x4 kip1 = *(const f32x4*)(kp + TSTR);        // kipre(t+1)
    unsigned char c0 = cp[0], c1v = cp[1];

    // y-partial store pointer (lane-strided, incremented by const per step)
    float* ypt = ypart + (size_t)(rb * 8 + w) * 64 + g * 16 + (cl >> 2);
    const size_t YSTR = (size_t)32 * 8 * 64;
    bool ystore = ((cl & 3) == 0);

    // prologue: d0 = x(0) - h0
    {
        f32x4 x0 = *(const f32x4*)(xp);
        #pragma unroll
        for (int i = 0; i < 4; ++i)
            *(unsigned short*)((char*)dbuf + offW[i]) = f2bf(x0[i] - h[i]);
    }
    bar_lgkm();

    #pragma unroll 2
    for (int t = 0; t < TT; ++t) {
        // ---- prefetch t+3 / t+2 stream data (never waited before next barrier) ----
        int t3 = (t + 3 <= 499) ? t + 3 : 499;
        int tk = (t + 2 <= 499) ? t + 2 : 499;
        f32x4 xn3  = *(const f32x4*)(xp + (size_t)t3 * TSTR);
        f32x4 kip2 = *(const f32x4*)(kp + (size_t)tk * TSTR);
        unsigned char c2v = cp[tk];

        // ---- phase 1: s1,s2 = d@Wsdf1/2 + bias ; gate acc = kipre - d@Wki0 ----
        f32x4 s1 = {bs1, bs1, bs1, bs1};
        f32x4 s2 = {bs2, bs2, bs2, bs2};
        f32x4 gd = kip;
        #pragma unroll
        for (int kt = 0; kt < 4; ++kt) {
            bf16x8 df = *(const bf16x8*)((char*)dbuf + offR[kt]);
            s1 = __builtin_amdgcn_mfma_f32_16x16x32_bf16(df, wf[0][kt], s1, 0, 0, 0);
            s2 = __builtin_amdgcn_mfma_f32_16x16x32_bf16(df, wf[1][kt], s2, 0, 0, 0);
            gd = __builtin_amdgcn_mfma_f32_16x16x32_bf16(df, wf[4][kt], gd, 0, 0, 0);
        }
        float gv[4];
        #pragma unroll
        for (int i = 0; i < 4; ++i) {
            float sdfv = sigtanh(s1[i], s2[i]);
            gv[i] = fsig(gd[i]);
            *(unsigned short*)((char*)sbuf + offW[i]) = f2bf(sdfv);
        }
        bar_lgkm();

        // ---- phase 2: p1,p2 = sdf@Wpka1/2 + selected bias ; h update ----
        f32x4 p1, p2;
        #pragma unroll
        for (int i = 0; i < 4; ++i) {
            bool bit = (c0 >> i) & 1;
            p1[i] = bit ? tp1b : tp1a;
            p2[i] = bit ? tp2b : tp2a;
        }
        #pragma unroll
        for (int kt = 0; kt < 4; ++kt) {
            bf16x8 sf = *(const bf16x8*)((char*)sbuf + offR[kt]);
            p1 = __builtin_amdgcn_mfma_f32_16x16x32_bf16(sf, wf[2][kt], p1, 0, 0, 0);
            p2 = __builtin_amdgcn_mfma_f32_16x16x32_bf16(sf, wf[3][kt], p2, 0, 0, 0);
        }
        #pragma unroll
        for (int i = 0; i < 4; ++i) {
            float pka = sigtanh(p1[i], p2[i]);
            h[i] = gv[i] * h[i] + (1.0f - gv[i]) * pka;
        }
        // ---- d-write for step t+1 IMMEDIATELY (critical path) ----
        #pragma unroll
        for (int i = 0; i < 4; ++i)
            *(unsigned short*)((char*)dbuf + offW[i]) = f2bf(xn[i] - h[i]);

        // ---- y partials (off critical path): DPP quad reduce, masked store ----
        #pragma unroll
        for (int i = 0; i < 4; ++i) {
            float yv = quad_sum(xn[i] * h[i]);
            if (ystore) ypt[i * 4] = yv;
        }
        ypt += YSTR;
        bar_lgkm();

        // rotate prefetch pipeline
        xn = xn2; xn2 = xn3; kip = kip1; kip1 = kip2; c0 = c1v; c1v = c2v;
    }
}

// ---------------- final: y[b][t] = sigmoid(sum of 32 partials); y[:,499] = 0 ----------------
__global__ __launch_bounds__(256) void k_yfinal(const float* __restrict__ ypart, float* __restrict__ y)
{
    int id = blockIdx.x * 256 + threadIdx.x;
    if (id >= BB * SS) return;
    int b = id / SS, t = id - b * SS;
    if (t == TT) { y[id] = 0.0f; return; }
    int rb = b >> 4, row = b & 15;
    float s = 0.0f;
    #pragma unroll
    for (int w = 0; w < 8; ++w) {
        f32x4 v = *(const f32x4*)&ypart[(((size_t)t * 32 + rb) * 8 + w) * 64 + (size_t)row * 4];
        s += v[0] + v[1] + v[2] + v[3];
    }
    y[id] = fsig(s);
}

// ---------------- launch ----------------
extern "C" void kernel_launch(void* const* d_in, const int* in_sizes, int n_in,
                              void* d_out, int out_size, void* d_ws, size_t ws_size,
                              hipStream_t stream) {
    const int* qs    = (const int*)d_in[0];
    const int* cs    = (const int*)d_in[1];
    const int* qds   = (const int*)d_in[2];
    const int* cds   = (const int*)d_in[3];
    const int* corr  = (const int*)d_in[4];
    const float* Eq    = (const float*)d_in[5];
    const float* Ec    = (const float*)d_in[6];
    const float* Eqd   = (const float*)d_in[7];
    const float* Ecd   = (const float*)d_in[8];
    const float* Ecorr = (const float*)d_in[9];
    const float* Wx    = (const float*)d_in[10];
    const float* bx    = (const float*)d_in[11];
    const float* Wsdf1 = (const float*)d_in[12];
    const float* bsdf1 = (const float*)d_in[13];
    const float* Wsdf2 = (const float*)d_in[14];
    const float* bsdf2 = (const float*)d_in[15];
    const float* Wpka1 = (const float*)d_in[16];
    const float* bpka1 = (const float*)d_in[17];
    const float* Wpka2 = (const float*)d_in[18];
    const float* bpka2 = (const float*)d_in[19];
    const float* Wki   = (const float*)d_in[20];
    const float* bki   = (const float*)d_in[21];
    const float* h0    = (const float*)d_in[22];

    char* base;
    if (ws_size >= TOTAL_WS) {
        base = (char*)d_ws;
    } else {
        void* p = nullptr;
        hipGetSymbolAddress(&p, HIP_SYMBOL(g_fb));
        base = (char*)p;
    }

    float* Txq   = (float*)(base + OFF_TXQ);
    float* Txc   = (float*)(base + OFF_TXC);
    float* Txqd  = (float*)(base + OFF_TXQD);
    float* Txcd  = (float*)(base + OFF_TXCD);
    float* TkiQd = (float*)(base + OFF_TKIQD);
    float* TkiCd = (float*)(base + OFF_TKICD);
    float* TkiCo = (float*)(base + OFF_TKICO);
    float* Tp1   = (float*)(base + OFF_TP1);
    float* Tp2   = (float*)(base + OFF_TP2);
    float* Txq2  = (float*)(base + OFF_TXQ2);
    float* Txc2  = (float*)(base + OFF_TXC2);
    unsigned short* wfrag = (unsigned short*)(base + OFF_WFRAG);
    unsigned char*  cpk   = (unsigned char*)(base + OFF_CPK);
    float* xcd   = (float*)(base + OFF_XCD);
    float* kipre = (float*)(base + OFF_KIPRE);
    float* ypart = (float*)(base + OFF_YPART);

    k_tables<<<10906, 128, 0, stream>>>(Eq, Ec, Eqd, Ecd, Ecorr, Wx, bx,
                                        Wpka1, bpka1, Wpka2, bpka2, Wki, bki,
                                        Txq, Txc, Txqd, Txcd, TkiQd, TkiCd, TkiCo, Tp1, Tp2);
    k_tables2<<<10700, 128, 0, stream>>>(Wki, Txq, Txc, Txqd, Txcd, Txq2, Txc2, TkiQd, TkiCd);
    k_wfrag<<<160, 64, 0, stream>>>(Wsdf1, Wsdf2, Wpka1, Wpka2, Wki, wfrag);
    k_gather<<<SS * NRB, 512, 0, stream>>>(qs, cs, qds, cds, corr,
                                           Txq, Txc, Txqd, Txcd, Txq2, Txc2,
                                           TkiQd, TkiCd, TkiCo, xcd, kipre, cpk);
    k_rec<<<NRB, 512, 0, stream>>>(xcd, kipre, cpk, wfrag, Tp1, Tp2,
                                   bsdf1, bsdf2, h0, ypart);
    k_yfinal<<<(BB * SS + 255) / 256, 256, 0, stream>>>(ypart, (float*)d_out);
}

// Round 5
// 641.578 us; speedup vs baseline: 2.2280x; 1.2908x over previous
//
#include <hip/hip_runtime.h>
#include <hip/hip_bf16.h>
#include <cstdint>
#include <cstddef>

// ---------------- problem constants ----------------
#define BB 512
#define SS 500
#define TT 499            // scan steps t = 0..498
#define NRB 64            // recurrence blocks (8 rows each)
#define L2E 1.4426950408889634f

typedef float  f32x4  __attribute__((ext_vector_type(4)));
typedef short  bf16x8 __attribute__((ext_vector_type(8)));

// ---------------- workspace layout (bytes) ----------------
static constexpr size_t OFF_TXQ   = 0;                 // 10000*128*4
static constexpr size_t OFF_TXC   = 5120000;           // 500*128*4
static constexpr size_t OFF_TXQD  = 5376000;           // 100*128*4
static constexpr size_t OFF_TXCD  = 5427200;           // 100*128*4
static constexpr size_t OFF_TKIQD = 5478400;           // 100*128*4 (+= Txqd@Wki0)
static constexpr size_t OFF_TKICD = 5529600;           // 100*128*4 (+= Txcd@Wki0)
static constexpr size_t OFF_TKICO = 5580800;           // 2*128*4 (pad 1024)
static constexpr size_t OFF_TP1   = 5581824;           // 2*128*4 (pad 1024), scaled -L2E
static constexpr size_t OFF_TP2   = 5582848;           // 2*128*4 (pad 1024), scaled -2*L2E
static constexpr size_t OFF_TXQ2  = 5583872;           // 10000*128*4 (Txq@Wki0)
static constexpr size_t OFF_TXC2  = 10703872;          // 500*128*4   (Txc@Wki0)
static constexpr size_t OFF_WFRAG = 10959872;          // 5*128*128*2 (pre-scaled bf16)
static constexpr size_t OFF_CPK   = 11123712;          // 64*512 bytes
static constexpr size_t OFF_XCD   = 11156480;          // 503*64*1024*4 (float2/lane layout)
static constexpr size_t OFF_KIPRE = 143014912;         // 503*64*1024*4 (scaled -L2E)
static constexpr size_t OFF_YPART = 274873344;         // 499*64*8*32*4
static constexpr size_t TOTAL_WS  = 307575808;

// fallback scratch if harness workspace is too small
__device__ unsigned char g_fb[TOTAL_WS];

// ---------------- helpers ----------------
__device__ __forceinline__ unsigned short f2bf(float f) {
    union { float f; uint32_t u; } v; v.f = f;
    uint32_t u = v.u;
    uint32_t r = u + 0x7FFFu + ((u >> 16) & 1u);
    return (unsigned short)(r >> 16);
}
__device__ __forceinline__ float fsig(float z) {
    return __builtin_amdgcn_rcpf(1.0f + __expf(-z));
}
// pack 2 f32 -> 2 bf16 (RTNE) in one instr: dst.lo = cvt(lo), dst.hi = cvt(hi)
__device__ __forceinline__ uint32_t cvtpk(float lo, float hi) {
    uint32_t r;
    asm("v_cvt_pk_bf16_f32 %0, %1, %2" : "=v"(r) : "v"(lo), "v"(hi));
    return r;
}
// barrier that only orders LDS traffic (prefetch loads stay in flight)
__device__ __forceinline__ void bar_lgkm() {
    asm volatile("s_waitcnt lgkmcnt(0)" ::: "memory");
    __builtin_amdgcn_s_barrier();
}
// sum over aligned lane quads via DPP quad_perm
__device__ __forceinline__ float quad_sum(float x) {
    int a = __float_as_int(x);
    int b = __builtin_amdgcn_update_dpp(a, a, 0xB1, 0xF, 0xF, false); // xor 1
    float s = x + __int_as_float(b);
    int c = __float_as_int(s);
    int d = __builtin_amdgcn_update_dpp(c, c, 0x4E, 0xF, 0xF, false); // xor 2
    return s + __int_as_float(d);
}

// ---------------- P1: per-table GEMM products ----------------
__global__ __launch_bounds__(128) void k_tables(
    const float* __restrict__ Eq, const float* __restrict__ Ec,
    const float* __restrict__ Eqd, const float* __restrict__ Ecd,
    const float* __restrict__ Ecorr,
    const float* __restrict__ Wx,  const float* __restrict__ bx,
    const float* __restrict__ Wpka1, const float* __restrict__ bpka1,
    const float* __restrict__ Wpka2, const float* __restrict__ bpka2,
    const float* __restrict__ Wki, const float* __restrict__ bki,
    float* __restrict__ Txq, float* __restrict__ Txc,
    float* __restrict__ Txqd, float* __restrict__ Txcd,
    float* __restrict__ TkiQd, float* __restrict__ TkiCd, float* __restrict__ TkiCo,
    float* __restrict__ Tp1, float* __restrict__ Tp2)
{
    int blk = blockIdx.x;
    const float* A; const float* W; const float* bias = nullptr; float* out; int row;
    float oscale = 1.0f;
    if      (blk < 10000) { A = Eq;    row = blk;          W = Wx;              bias = bx;    out = Txq;  }
    else if (blk < 10500) { A = Ec;    row = blk - 10000;  W = Wx  + 128*128;                 out = Txc;  }
    else if (blk < 10600) { A = Eqd;   row = blk - 10500;  W = Wx  + 256*128;                 out = Txqd; }
    else if (blk < 10700) { A = Ecd;   row = blk - 10600;  W = Wx  + 384*128;                 out = Txcd; }
    else if (blk < 10800) { A = Eqd;   row = blk - 10700;  W = Wki + 256*128;                 out = TkiQd;}
    else if (blk < 10900) { A = Ecd;   row = blk - 10800;  W = Wki + 384*128;                 out = TkiCd;}
    else if (blk < 10902) { A = Ecorr; row = blk - 10900;  W = Wki + 128*128;   bias = bki;   out = TkiCo;}
    else if (blk < 10904) { A = Ecorr; row = blk - 10902;  W = Wpka1 + 128*128; bias = bpka1; out = Tp1;  oscale = -L2E; }
    else                  { A = Ecorr; row = blk - 10904;  W = Wpka2 + 128*128; bias = bpka2; out = Tp2;  oscale = -2.0f*L2E; }

    __shared__ float a[128];
    int c = threadIdx.x;
    a[c] = A[row * 128 + c];
    __syncthreads();
    float acc = bias ? bias[c] : 0.0f;
    #pragma unroll 8
    for (int k = 0; k < 128; ++k) acc += a[k] * W[k * 128 + c];
    out[row * 128 + c] = acc * oscale;
}

// ---------------- P1b: fold x@Wki0 into tables ----------------
__global__ __launch_bounds__(128) void k_tables2(
    const float* __restrict__ Wki,
    const float* __restrict__ Txq, const float* __restrict__ Txc,
    const float* __restrict__ Txqd, const float* __restrict__ Txcd,
    float* __restrict__ Txq2, float* __restrict__ Txc2,
    float* __restrict__ TkiQd, float* __restrict__ TkiCd)
{
    int blk = blockIdx.x;
    const float* A; float* out; int row; bool accum;
    if      (blk < 10000) { A = Txq;  row = blk;          out = Txq2;  accum = false; }
    else if (blk < 10500) { A = Txc;  row = blk - 10000;  out = Txc2;  accum = false; }
    else if (blk < 10600) { A = Txqd; row = blk - 10500;  out = TkiQd; accum = true;  }
    else                  { A = Txcd; row = blk - 10600;  out = TkiCd; accum = true;  }
    __shared__ float a[128];
    int c = threadIdx.x;
    a[c] = A[row * 128 + c];
    __syncthreads();
    float acc = accum ? out[row * 128 + c] : 0.0f;
    #pragma unroll 8
    for (int k = 0; k < 128; ++k) acc += a[k] * Wki[k * 128 + c];
    out[row * 128 + c] = acc;
}

// ---------------- P0: weight matrices -> MFMA B-fragments (bf16, exp2-prescaled) ----
// scales: Wsdf1 -L2E | Wsdf2 -2L2E | Wpka1 -L2E | Wpka2 -2L2E | Wki0 +L2E
__global__ __launch_bounds__(64) void k_wfrag(
    const float* __restrict__ Wsdf1, const float* __restrict__ Wsdf2,
    const float* __restrict__ Wpka1, const float* __restrict__ Wpka2,
    const float* __restrict__ Wki, unsigned short* __restrict__ wfrag)
{
    int bid = blockIdx.x;                 // 5 * 8 * 4 = 160
    int m = bid >> 5, w = (bid >> 2) & 7, kt = bid & 3;
    const float* W = (m == 0) ? Wsdf1 : (m == 1) ? Wsdf2 : (m == 2) ? Wpka1 : (m == 3) ? Wpka2 : Wki;
    float sgn = (m == 0) ? -L2E : (m == 1) ? -2.0f*L2E : (m == 2) ? -L2E : (m == 3) ? -2.0f*L2E : L2E;
    int l = threadIdx.x;
    int cc = w * 16 + (l & 15);
    int k0 = kt * 32 + ((l >> 4) << 3);
    unsigned short v[8];
    #pragma unroll
    for (int j = 0; j < 8; ++j) v[j] = f2bf(sgn * W[(size_t)(k0 + j) * 128 + cc]);
    unsigned short* dst = wfrag + ((( (size_t)m * 8 + w) * 4 + kt) * 64 + l) * 8;
    #pragma unroll
    for (int j = 0; j < 8; ++j) dst[j] = v[j];
}

// ---------------- P2: materialize x / kipre in the 2-element redistributed layout ----
// per (t, rb<64): 512 lanes x float2; lane (w,l): rows (row0, row0+1), col = w*16+(l&15)
__global__ __launch_bounds__(512) void k_gather(
    const int* __restrict__ qs, const int* __restrict__ cs,
    const int* __restrict__ qds, const int* __restrict__ cds, const int* __restrict__ corr,
    const float* __restrict__ Txq, const float* __restrict__ Txc,
    const float* __restrict__ Txqd, const float* __restrict__ Txcd,
    const float* __restrict__ Txq2, const float* __restrict__ Txc2,
    const float* __restrict__ TkiQd, const float* __restrict__ TkiCd, const float* __restrict__ TkiCo,
    float* __restrict__ xcd, float* __restrict__ kipre, unsigned char* __restrict__ cpk)
{
    int bid = blockIdx.x;
    int t = bid >> 6, rb = bid & 63;
    __shared__ float xl[8][132];
    __shared__ float kl[8][132];
    __shared__ int idx[5][8];
    int tid = threadIdx.x;
    if (tid < 40) {
        int which = tid >> 3, row = tid & 7;
        const int* P = (which == 0) ? qs : (which == 1) ? cs : (which == 2) ? qds : (which == 3) ? cds : corr;
        idx[which][row] = P[(size_t)(rb * 8 + row) * SS + t];
    }
    __syncthreads();
    {
        int row = tid >> 6; int c0 = (tid & 63) * 2;
        float2 xq = *(const float2*)&Txq [(size_t)idx[0][row] * 128 + c0];
        float2 xc = *(const float2*)&Txc [(size_t)idx[1][row] * 128 + c0];
        float2 xd = *(const float2*)&Txqd[(size_t)idx[2][row] * 128 + c0];
        float2 xe = *(const float2*)&Txcd[(size_t)idx[3][row] * 128 + c0];
        float2 k0 = *(const float2*)&Txq2[(size_t)idx[0][row] * 128 + c0];
        float2 k4 = *(const float2*)&Txc2[(size_t)idx[1][row] * 128 + c0];
        float2 k1 = *(const float2*)&TkiQd[(size_t)idx[2][row] * 128 + c0];
        float2 k2 = *(const float2*)&TkiCd[(size_t)idx[3][row] * 128 + c0];
        float2 k3 = *(const float2*)&TkiCo[(size_t)idx[4][row] * 128 + c0];
        xl[row][c0]     = xq.x + xc.x + xd.x + xe.x;
        xl[row][c0 + 1] = xq.y + xc.y + xd.y + xe.y;
        kl[row][c0]     = (k0.x + k4.x + k1.x + k2.x + k3.x) * (-L2E);
        kl[row][c0 + 1] = (k0.y + k4.y + k1.y + k2.y + k3.y) * (-L2E);
    }
    __syncthreads();
    {
        int w = tid >> 6, l = tid & 63;
        int row0 = ((l >> 4) & 1) * 4 + ((l >> 5) & 1) * 2;
        int col = w * 16 + (l & 15);
        float2 xo = { xl[row0][col], xl[row0 + 1][col] };
        float2 ko = { kl[row0][col], kl[row0 + 1][col] };
        ((float2*)xcd)[(size_t)bid * 512 + tid]   = xo;
        ((float2*)kipre)[(size_t)bid * 512 + tid] = ko;
    }
    if (tid == 0) {
        unsigned char b = 0;
        #pragma unroll
        for (int r = 0; r < 8; ++r) b |= (unsigned char)((idx[4][r] & 1) << r);
        cpk[(size_t)rb * 512 + t] = b;
    }
}

// ---------------- recurrence: 64 blocks x 512 threads (8 waves, 8 rows/block) ----------
// A-tile trick: LDS stores only 8 rows; fragment reads use row = cl&7, so tile rows
// 8-15 are DUPLICATES of 0-7. MFMA C rows 8-15 then duplicate rows 0-7, so lanes
// 32-63 hold valid copies in regs {2,3}: each lane selects its 2 owned elements
// (rows row0, row0+1) with a cndmask — no cross-lane data movement at all.
__global__ __launch_bounds__(512, 2) void k_rec(
    const float* __restrict__ xcd, const float* __restrict__ kipre,
    const unsigned char* __restrict__ cpkg,
    const unsigned short* __restrict__ wfrag,
    const float* __restrict__ Tp1, const float* __restrict__ Tp2,
    const float* __restrict__ bsdf1, const float* __restrict__ bsdf2,
    const float* __restrict__ h0, float* __restrict__ ypart)
{
    int rb = blockIdx.x;
    int tid = threadIdx.x;
    int w = tid >> 6, l = tid & 63;
    int g = l >> 4, cl = l & 15;
    int col = w * 16 + cl;
    int hi = l >> 5;                                       // 0: regs{0,1}, 1: regs{2,3}
    int row0 = ((l >> 4) & 1) * 4 + ((l >> 5) & 1) * 2;    // lanes: 0-15->0, 16-31->4, 32-47->2, 48-63->6

    __shared__ __align__(16) unsigned short dbuf[1024];    // 8 rows x 128 cols bf16
    __shared__ __align__(16) unsigned short sbuf[1024];

    // weight B-fragments (5 matrices x 4 k-tiles), exp2-prescaled
    bf16x8 wf[5][4];
    #pragma unroll
    for (int m = 0; m < 5; ++m)
        #pragma unroll
        for (int kt = 0; kt < 4; ++kt)
            wf[m][kt] = *(const bf16x8*)(wfrag + ((((size_t)m * 8 + w) * 4 + kt) * 64 + l) * 8);

    float bs1 = bsdf1[col] * (-L2E);
    float bs2 = bsdf2[col] * (-2.0f * L2E);
    float tp1a = Tp1[col], tp1b = Tp1[128 + col];   // pre-scaled -L2E
    float tp2a = Tp2[col], tp2b = Tp2[128 + col];   // pre-scaled -2L2E

    float hA = h0[(size_t)(rb * 8 + row0) * 128 + col];
    float hB = h0[(size_t)(rb * 8 + row0 + 1) * 128 + col];

    // hoisted LDS byte pointers (XOR-swizzled; write rows 0..7, read rows cl&7)
    char* pdw0 = (char*)dbuf + (((row0)     * 256 + col * 2) ^ ((row0)     << 4));
    char* pdw1 = (char*)dbuf + (((row0 + 1) * 256 + col * 2) ^ ((row0 + 1) << 4));
    char* psw0 = (char*)sbuf + (((row0)     * 256 + col * 2) ^ ((row0)     << 4));
    char* psw1 = (char*)sbuf + (((row0 + 1) * 256 + col * 2) ^ ((row0 + 1) << 4));
    const bf16x8* prd[4]; const bf16x8* prs[4];
    int rrow = cl & 7;
    #pragma unroll
    for (int kt = 0; kt < 4; ++kt) {
        int off = rrow * 256 + (((4 * kt + g) ^ rrow) << 4);
        prd[kt] = (const bf16x8*)((char*)dbuf + off);
        prs[kt] = (const bf16x8*)((char*)sbuf + off);
    }

    const size_t T2STR = 64 * 512;   // per-t stride in float2 units
    const float2* xp = (const float2*)xcd + (size_t)rb * 512 + tid;
    const float2* kp = (const float2*)kipre + (size_t)rb * 512 + tid;
    const unsigned char* cp = cpkg + (size_t)rb * 512;

    // prefetch pipeline (depth 2; arrays padded to t=502, no clamps)
    float2 xn   = xp[T2STR];
    float2 xn2  = xp[2 * T2STR];
    float2 kip  = kp[0];
    float2 kip1 = kp[T2STR];
    unsigned char c0 = cp[0], c1v = cp[1];

    // y-partial pointer: ypart[t][rb][w][row*4 + quad]
    float* ypt = ypart + (size_t)(rb * 8 + w) * 32 + row0 * 4 + (cl >> 2);
    const size_t YSTR = (size_t)NRB * 8 * 32;
    bool ystore = ((cl & 3) == 0);

    // prologue: d0 = x(0) - h0
    {
        float2 x0 = xp[0];
        uint32_t pk = cvtpk(x0.x - hA, x0.y - hB);
        *(unsigned short*)pdw0 = (unsigned short)pk;
        *(unsigned short*)pdw1 = (unsigned short)(pk >> 16);
    }
    bar_lgkm();

    #pragma unroll 2
    for (int t = 0; t < TT; ++t) {
        // ---- prefetch (never waited before next barrier) ----
        float2 xn3  = xp[(size_t)(t + 3) * T2STR];
        float2 kip2 = kp[(size_t)(t + 2) * T2STR];
        unsigned char c2v = cp[t + 2];

        // ---- phase 1: s1,s2 = d@Wsdf (scaled); gd = d@(L2E*Wki0) ----
        f32x4 s1 = {bs1, bs1, bs1, bs1};
        f32x4 s2 = {bs2, bs2, bs2, bs2};
        f32x4 gd = {0.f, 0.f, 0.f, 0.f};
        #pragma unroll
        for (int kt = 0; kt < 4; ++kt) {
            bf16x8 df = *prd[kt];
            s1 = __builtin_amdgcn_mfma_f32_16x16x32_bf16(df, wf[0][kt], s1, 0, 0, 0);
            s2 = __builtin_amdgcn_mfma_f32_16x16x32_bf16(df, wf[1][kt], s2, 0, 0, 0);
            gd = __builtin_amdgcn_mfma_f32_16x16x32_bf16(df, wf[4][kt], gd, 0, 0, 0);
        }
        // select owned elements (dup rows: lanes>=32 use regs {2,3})
        float s1A = hi ? s1[2] : s1[0], s1B = hi ? s1[3] : s1[1];
        float s2A = hi ? s2[2] : s2[0], s2B = hi ? s2[3] : s2[1];
        float gdA = hi ? gd[2] : gd[0], gdB = hi ? gd[3] : gd[1];
        float gvA = __builtin_amdgcn_rcpf(1.0f + __builtin_amdgcn_exp2f(gdA + kip.x));
        float gvB = __builtin_amdgcn_rcpf(1.0f + __builtin_amdgcn_exp2f(gdB + kip.y));
        float e1A = __builtin_amdgcn_exp2f(s1A), e2A = __builtin_amdgcn_exp2f(s2A);
        float e1B = __builtin_amdgcn_exp2f(s1B), e2B = __builtin_amdgcn_exp2f(s2B);
        float sdfA = (1.0f - e2A) * __builtin_amdgcn_rcpf((1.0f + e1A) * (1.0f + e2A));
        float sdfB = (1.0f - e2B) * __builtin_amdgcn_rcpf((1.0f + e1B) * (1.0f + e2B));
        {
            uint32_t pk = cvtpk(sdfA, sdfB);
            *(unsigned short*)psw0 = (unsigned short)pk;
            *(unsigned short*)psw1 = (unsigned short)(pk >> 16);
        }
        bar_lgkm();

        // ---- phase 2: p1,p2 = sdf@Wpka (scaled); bias-select post-select ----
        f32x4 p1 = {0.f, 0.f, 0.f, 0.f};
        f32x4 p2 = {0.f, 0.f, 0.f, 0.f};
        #pragma unroll
        for (int kt = 0; kt < 4; ++kt) {
            bf16x8 sf = *prs[kt];
            p1 = __builtin_amdgcn_mfma_f32_16x16x32_bf16(sf, wf[2][kt], p1, 0, 0, 0);
            p2 = __builtin_amdgcn_mfma_f32_16x16x32_bf16(sf, wf[3][kt], p2, 0, 0, 0);
        }
        float p1A = hi ? p1[2] : p1[0], p1B = hi ? p1[3] : p1[1];
        float p2A = hi ? p2[2] : p2[0], p2B = hi ? p2[3] : p2[1];
        unsigned int crow = ((unsigned int)c0) >> row0;
        float t1A = (crow & 1u) ? tp1b : tp1a;
        float t2A = (crow & 1u) ? tp2b : tp2a;
        float t1B = (crow & 2u) ? tp1b : tp1a;
        float t2B = (crow & 2u) ? tp2b : tp2a;
        float e1pA = __builtin_amdgcn_exp2f(p1A + t1A), e2pA = __builtin_amdgcn_exp2f(p2A + t2A);
        float e1pB = __builtin_amdgcn_exp2f(p1B + t1B), e2pB = __builtin_amdgcn_exp2f(p2B + t2B);
        float pkaA = (1.0f - e2pA) * __builtin_amdgcn_rcpf((1.0f + e1pA) * (1.0f + e2pA));
        float pkaB = (1.0f - e2pB) * __builtin_amdgcn_rcpf((1.0f + e1pB) * (1.0f + e2pB));
        hA = gvA * (hA - pkaA) + pkaA;
        hB = gvB * (hB - pkaB) + pkaB;

        // ---- d-write for step t+1 IMMEDIATELY (critical path) ----
        {
            uint32_t pk = cvtpk(xn.x - hA, xn.y - hB);
            *(unsigned short*)pdw0 = (unsigned short)pk;
            *(unsigned short*)pdw1 = (unsigned short)(pk >> 16);
        }
        // ---- y partials (off critical path) ----
        float yA = quad_sum(xn.x * hA);
        float yB = quad_sum(xn.y * hB);
        if (ystore) { ypt[0] = yA; ypt[4] = yB; }
        ypt += YSTR;
        bar_lgkm();

        // rotate prefetch pipeline
        xn = xn2; xn2 = xn3; kip = kip1; kip1 = kip2; c0 = c1v; c1v = c2v;
    }
}

// ---------------- final: y[b][t] = sigmoid(sum of 8x4 partials); y[:,499] = 0 ----------------
__global__ __launch_bounds__(256) void k_yfinal(const float* __restrict__ ypart, float* __restrict__ y)
{
    int id = blockIdx.x * 256 + threadIdx.x;
    if (id >= BB * SS) return;
    int b = id / SS, t = id - b * SS;
    if (t == TT) { y[id] = 0.0f; return; }
    int rb = b >> 3, r = b & 7;
    float s = 0.0f;
    #pragma unroll
    for (int w = 0; w < 8; ++w) {
        f32x4 v = *(const f32x4*)&ypart[(size_t)t * 16384 + (size_t)(rb * 8 + w) * 32 + r * 4];
        s += v[0] + v[1] + v[2] + v[3];
    }
    y[id] = fsig(s);
}

// ---------------- launch ----------------
extern "C" void kernel_launch(void* const* d_in, const int* in_sizes, int n_in,
                              void* d_out, int out_size, void* d_ws, size_t ws_size,
                              hipStream_t stream) {
    const int* qs    = (const int*)d_in[0];
    const int* cs    = (const int*)d_in[1];
    const int* qds   = (const int*)d_in[2];
    const int* cds   = (const int*)d_in[3];
    const int* corr  = (const int*)d_in[4];
    const float* Eq    = (const float*)d_in[5];
    const float* Ec    = (const float*)d_in[6];
    const float* Eqd   = (const float*)d_in[7];
    const float* Ecd   = (const float*)d_in[8];
    const float* Ecorr = (const float*)d_in[9];
    const float* Wx    = (const float*)d_in[10];
    const float* bx    = (const float*)d_in[11];
    const float* Wsdf1 = (const float*)d_in[12];
    const float* bsdf1 = (const float*)d_in[13];
    const float* Wsdf2 = (const float*)d_in[14];
    const float* bsdf2 = (const float*)d_in[15];
    const float* Wpka1 = (const float*)d_in[16];
    const float* bpka1 = (const float*)d_in[17];
    const float* Wpka2 = (const float*)d_in[18];
    const float* bpka2 = (const float*)d_in[19];
    const float* Wki   = (const float*)d_in[20];
    const float* bki   = (const float*)d_in[21];
    const float* h0    = (const float*)d_in[22];

    char* base;
    if (ws_size >= TOTAL_WS) {
        base = (char*)d_ws;
    } else {
        void* p = nullptr;
        hipGetSymbolAddress(&p, HIP_SYMBOL(g_fb));
        base = (char*)p;
    }

    float* Txq   = (float*)(base + OFF_TXQ);
    float* Txc   = (float*)(base + OFF_TXC);
    float* Txqd  = (float*)(base + OFF_TXQD);
    float* Txcd  = (float*)(base + OFF_TXCD);
    float* TkiQd = (float*)(base + OFF_TKIQD);
    float* TkiCd = (float*)(base + OFF_TKICD);
    float* TkiCo = (float*)(base + OFF_TKICO);
    float* Tp1   = (float*)(base + OFF_TP1);
    float* Tp2   = (float*)(base + OFF_TP2);
    float* Txq2  = (float*)(base + OFF_TXQ2);
    float* Txc2  = (float*)(base + OFF_TXC2);
    unsigned short* wfrag = (unsigned short*)(base + OFF_WFRAG);
    unsigned char*  cpk   = (unsigned char*)(base + OFF_CPK);
    float* xcd   = (float*)(base + OFF_XCD);
    float* kipre = (float*)(base + OFF_KIPRE);
    float* ypart = (float*)(base + OFF_YPART);

    k_tables<<<10906, 128, 0, stream>>>(Eq, Ec, Eqd, Ecd, Ecorr, Wx, bx,
                                        Wpka1, bpka1, Wpka2, bpka2, Wki, bki,
                                        Txq, Txc, Txqd, Txcd, TkiQd, TkiCd, TkiCo, Tp1, Tp2);
    k_tables2<<<10700, 128, 0, stream>>>(Wki, Txq, Txc, Txqd, Txcd, Txq2, Txc2, TkiQd, TkiCd);
    k_wfrag<<<160, 64, 0, stream>>>(Wsdf1, Wsdf2, Wpka1, Wpka2, Wki, wfrag);
    k_gather<<<SS * NRB, 512, 0, stream>>>(qs, cs, qds, cds, corr,
                                           Txq, Txc, Txqd, Txcd, Txq2, Txc2,
                                           TkiQd, TkiCd, TkiCo, xcd, kipre, cpk);
    k_rec<<<NRB, 512, 0, stream>>>(xcd, kipre, cpk, wfrag, Tp1, Tp2,
                                   bsdf1, bsdf2, h0, ypart);
    k_yfinal<<<(BB * SS + 255) / 256, 256, 0, stream>>>(ypart, (float*)d_out);
}

// Round 6
// 557.942 us; speedup vs baseline: 2.5619x; 1.1499x over previous
//
#include <hip/hip_runtime.h>
#include <hip/hip_bf16.h>
#include <cstdint>
#include <cstddef>

// ---------------- problem constants ----------------
#define BB 512
#define SS 500
#define TT 499            // scan steps t = 0..498
#define NRB 128           // recurrence blocks (4 rows each)
#define L2E 1.4426950408889634f

typedef float  f32x4  __attribute__((ext_vector_type(4)));
typedef short  bf16x8 __attribute__((ext_vector_type(8)));

// ---------------- workspace layout (bytes) ----------------
static constexpr size_t OFF_TXQ   = 0;                 // 10000*128*4
static constexpr size_t OFF_TXC   = 5120000;           // 500*128*4
static constexpr size_t OFF_TXQD  = 5376000;           // 100*128*4
static constexpr size_t OFF_TXCD  = 5427200;           // 100*128*4
static constexpr size_t OFF_TKIQD = 5478400;           // 100*128*4 (+= Txqd@Wki0)
static constexpr size_t OFF_TKICD = 5529600;           // 100*128*4 (+= Txcd@Wki0)
static constexpr size_t OFF_TKICO = 5580800;           // 2*128*4 (pad 1024)
static constexpr size_t OFF_TP1   = 5581824;           // 2*128*4 (pad 1024), scaled -L2E
static constexpr size_t OFF_TP2   = 5582848;           // 2*128*4 (pad 1024), scaled -2*L2E
static constexpr size_t OFF_TXQ2  = 5583872;           // 10000*128*4 (Txq@Wki0)
static constexpr size_t OFF_TXC2  = 10703872;          // 500*128*4   (Txc@Wki0)
static constexpr size_t OFF_WFRAG = 10959872;          // 5*128*128*2 (pre-scaled bf16)
static constexpr size_t OFF_CPK   = 11123712;          // 128*512 bytes
static constexpr size_t OFF_XCD   = 11189248;          // 504*128*512*4 (1 f32/lane layout)
static constexpr size_t OFF_KIPRE = 143309824;         // 504*128*512*4 (scaled -L2E)
static constexpr size_t OFF_YPART = 275430400;         // 499*128*8*4*4
static constexpr size_t TOTAL_WS  = 283606016;

// fallback scratch if harness workspace is too small
__device__ unsigned char g_fb[TOTAL_WS];

// ---------------- helpers ----------------
__device__ __forceinline__ unsigned short f2bf(float f) {
    union { float f; uint32_t u; } v; v.f = f;
    uint32_t u = v.u;
    uint32_t r = u + 0x7FFFu + ((u >> 16) & 1u);
    return (unsigned short)(r >> 16);
}
__device__ __forceinline__ float fsig(float z) {
    return __builtin_amdgcn_rcpf(1.0f + __expf(-z));
}
// pack 2 f32 -> 2 bf16 (RTNE): dst.lo = cvt(lo), dst.hi = cvt(hi)
__device__ __forceinline__ uint32_t cvtpk(float lo, float hi) {
    uint32_t r;
    asm("v_cvt_pk_bf16_f32 %0, %1, %2" : "=v"(r) : "v"(lo), "v"(hi));
    return r;
}
// barrier that only orders LDS traffic (prefetch loads stay in flight)
__device__ __forceinline__ void bar_lgkm() {
    asm volatile("s_waitcnt lgkmcnt(0)" ::: "memory");
    __builtin_amdgcn_s_barrier();
}
// sum over each 16-lane group via DPP (quad xor1, xor2, half-mirror, mirror)
__device__ __forceinline__ float sum16(float x) {
    int a = __float_as_int(x);
    int b = __builtin_amdgcn_update_dpp(a, a, 0xB1, 0xF, 0xF, false);   // quad xor1
    float s = x + __int_as_float(b);
    int c = __float_as_int(s);
    int d = __builtin_amdgcn_update_dpp(c, c, 0x4E, 0xF, 0xF, false);   // quad xor2
    s += __int_as_float(d);
    int e = __float_as_int(s);
    int f = __builtin_amdgcn_update_dpp(e, e, 0x141, 0xF, 0xF, false);  // row_half_mirror
    s += __int_as_float(f);
    int gg = __float_as_int(s);
    int hh = __builtin_amdgcn_update_dpp(gg, gg, 0x140, 0xF, 0xF, false); // row_mirror
    return s + __int_as_float(hh);
}
// select reg g (g in 0..3, per-lane) from a f32x4 with static indices
__device__ __forceinline__ float sel4(f32x4 a, int g) {
    float x01 = (g & 1) ? a[1] : a[0];
    float x23 = (g & 1) ? a[3] : a[2];
    return (g & 2) ? x23 : x01;
}

// ---------------- P1: per-table GEMM products ----------------
__global__ __launch_bounds__(128) void k_tables(
    const float* __restrict__ Eq, const float* __restrict__ Ec,
    const float* __restrict__ Eqd, const float* __restrict__ Ecd,
    const float* __restrict__ Ecorr,
    const float* __restrict__ Wx,  const float* __restrict__ bx,
    const float* __restrict__ Wpka1, const float* __restrict__ bpka1,
    const float* __restrict__ Wpka2, const float* __restrict__ bpka2,
    const float* __restrict__ Wki, const float* __restrict__ bki,
    float* __restrict__ Txq, float* __restrict__ Txc,
    float* __restrict__ Txqd, float* __restrict__ Txcd,
    float* __restrict__ TkiQd, float* __restrict__ TkiCd, float* __restrict__ TkiCo,
    float* __restrict__ Tp1, float* __restrict__ Tp2)
{
    int blk = blockIdx.x;
    const float* A; const float* W; const float* bias = nullptr; float* out; int row;
    float oscale = 1.0f;
    if      (blk < 10000) { A = Eq;    row = blk;          W = Wx;              bias = bx;    out = Txq;  }
    else if (blk < 10500) { A = Ec;    row = blk - 10000;  W = Wx  + 128*128;                 out = Txc;  }
    else if (blk < 10600) { A = Eqd;   row = blk - 10500;  W = Wx  + 256*128;                 out = Txqd; }
    else if (blk < 10700) { A = Ecd;   row = blk - 10600;  W = Wx  + 384*128;                 out = Txcd; }
    else if (blk < 10800) { A = Eqd;   row = blk - 10700;  W = Wki + 256*128;                 out = TkiQd;}
    else if (blk < 10900) { A = Ecd;   row = blk - 10800;  W = Wki + 384*128;                 out = TkiCd;}
    else if (blk < 10902) { A = Ecorr; row = blk - 10900;  W = Wki + 128*128;   bias = bki;   out = TkiCo;}
    else if (blk < 10904) { A = Ecorr; row = blk - 10902;  W = Wpka1 + 128*128; bias = bpka1; out = Tp1;  oscale = -L2E; }
    else                  { A = Ecorr; row = blk - 10904;  W = Wpka2 + 128*128; bias = bpka2; out = Tp2;  oscale = -2.0f*L2E; }

    __shared__ float a[128];
    int c = threadIdx.x;
    a[c] = A[row * 128 + c];
    __syncthreads();
    float acc = bias ? bias[c] : 0.0f;
    #pragma unroll 8
    for (int k = 0; k < 128; ++k) acc += a[k] * W[k * 128 + c];
    out[row * 128 + c] = acc * oscale;
}

// ---------------- P1b: fold x@Wki0 into tables ----------------
__global__ __launch_bounds__(128) void k_tables2(
    const float* __restrict__ Wki,
    const float* __restrict__ Txq, const float* __restrict__ Txc,
    const float* __restrict__ Txqd, const float* __restrict__ Txcd,
    float* __restrict__ Txq2, float* __restrict__ Txc2,
    float* __restrict__ TkiQd, float* __restrict__ TkiCd)
{
    int blk = blockIdx.x;
    const float* A; float* out; int row; bool accum;
    if      (blk < 10000) { A = Txq;  row = blk;          out = Txq2;  accum = false; }
    else if (blk < 10500) { A = Txc;  row = blk - 10000;  out = Txc2;  accum = false; }
    else if (blk < 10600) { A = Txqd; row = blk - 10500;  out = TkiQd; accum = true;  }
    else                  { A = Txcd; row = blk - 10600;  out = TkiCd; accum = true;  }
    __shared__ float a[128];
    int c = threadIdx.x;
    a[c] = A[row * 128 + c];
    __syncthreads();
    float acc = accum ? out[row * 128 + c] : 0.0f;
    #pragma unroll 8
    for (int k = 0; k < 128; ++k) acc += a[k] * Wki[k * 128 + c];
    out[row * 128 + c] = acc;
}

// ---------------- P0: weight matrices -> MFMA B-fragments (bf16, exp2-prescaled) ----
// scales: Wsdf1 -L2E | Wsdf2 -2L2E | Wpka1 -L2E | Wpka2 -2L2E | Wki0 +L2E
__global__ __launch_bounds__(64) void k_wfrag(
    const float* __restrict__ Wsdf1, const float* __restrict__ Wsdf2,
    const float* __restrict__ Wpka1, const float* __restrict__ Wpka2,
    const float* __restrict__ Wki, unsigned short* __restrict__ wfrag)
{
    int bid = blockIdx.x;                 // 5 * 8 * 4 = 160
    int m = bid >> 5, w = (bid >> 2) & 7, kt = bid & 3;
    const float* W = (m == 0) ? Wsdf1 : (m == 1) ? Wsdf2 : (m == 2) ? Wpka1 : (m == 3) ? Wpka2 : Wki;
    float sgn = (m == 0) ? -L2E : (m == 1) ? -2.0f*L2E : (m == 2) ? -L2E : (m == 3) ? -2.0f*L2E : L2E;
    int l = threadIdx.x;
    int cc = w * 16 + (l & 15);
    int k0 = kt * 32 + ((l >> 4) << 3);
    unsigned short v[8];
    #pragma unroll
    for (int j = 0; j < 8; ++j) v[j] = f2bf(sgn * W[(size_t)(k0 + j) * 128 + cc]);
    unsigned short* dst = wfrag + ((( (size_t)m * 8 + w) * 4 + kt) * 64 + l) * 8;
    #pragma unroll
    for (int j = 0; j < 8; ++j) dst[j] = v[j];
}

// ---------------- P2: materialize x / kipre, 1 f32 per (t, rb, lane) ----------------
// lane (tid): row g = (tid>>4)&3 (global row rb*4+g), col = (tid>>6)*16 + (tid&15)
__global__ __launch_bounds__(512) void k_gather(
    const int* __restrict__ qs, const int* __restrict__ cs,
    const int* __restrict__ qds, const int* __restrict__ cds, const int* __restrict__ corr,
    const float* __restrict__ Txq, const float* __restrict__ Txc,
    const float* __restrict__ Txqd, const float* __restrict__ Txcd,
    const float* __restrict__ Txq2, const float* __restrict__ Txc2,
    const float* __restrict__ TkiQd, const float* __restrict__ TkiCd, const float* __restrict__ TkiCo,
    float* __restrict__ xcd, float* __restrict__ kipre, unsigned char* __restrict__ cpk)
{
    int bid = blockIdx.x;            // bid = t*128 + rb
    int t = bid >> 7, rb = bid & 127;
    int tid = threadIdx.x;
    int g = (tid >> 4) & 3;
    int col = (tid >> 6) * 16 + (tid & 15);
    int b = rb * 4 + g;

    int iq  = qs  [(size_t)b * SS + t];
    int ic  = cs  [(size_t)b * SS + t];
    int iqd = qds [(size_t)b * SS + t];
    int icd = cds [(size_t)b * SS + t];
    int ico = corr[(size_t)b * SS + t];

    float x = Txq [(size_t)iq  * 128 + col] + Txc [(size_t)ic  * 128 + col]
            + Txqd[(size_t)iqd * 128 + col] + Txcd[(size_t)icd * 128 + col];
    float k = (Txq2 [(size_t)iq  * 128 + col] + Txc2 [(size_t)ic  * 128 + col]
             + TkiQd[(size_t)iqd * 128 + col] + TkiCd[(size_t)icd * 128 + col]
             + TkiCo[(size_t)ico * 128 + col]) * (-L2E);

    xcd  [(size_t)bid * 512 + tid] = x;
    kipre[(size_t)bid * 512 + tid] = k;

    if (tid == 0) {
        unsigned char bpk = 0;
        #pragma unroll
        for (int r = 0; r < 4; ++r)
            bpk |= (unsigned char)((corr[(size_t)(rb * 4 + r) * SS + t] & 1) << r);
        cpk[(size_t)rb * 512 + t] = bpk;
    }
}

// ---------------- recurrence: 128 blocks x 512 threads (8 waves, 4 rows/block) --------
// Dup-4 A-tile: LDS holds 4 rows; fragment reads use rrow = cl&3, so physical A rows
// p carry logical row p mod 4. Then C reg i = logical row i for EVERY lane; each lane
// owns one element (row g = l>>4, col w*16+(l&15)) selected by a 2-level cndmask tree.
// LDS swizzle: 16B-line index ^= row<<1 (reads conflict-free per quarter).
__global__ __launch_bounds__(512, 2) void k_rec(
    const float* __restrict__ xcd, const float* __restrict__ kipre,
    const unsigned char* __restrict__ cpkg,
    const unsigned short* __restrict__ wfrag,
    const float* __restrict__ Tp1, const float* __restrict__ Tp2,
    const float* __restrict__ bsdf1, const float* __restrict__ bsdf2,
    const float* __restrict__ h0, float* __restrict__ ypart)
{
    int rb = blockIdx.x;
    int tid = threadIdx.x;
    int w = tid >> 6, l = tid & 63;
    int g = l >> 4, cl = l & 15;
    int col = w * 16 + cl;

    __shared__ __align__(16) unsigned short dbuf[512];   // 4 rows x 128 cols bf16
    __shared__ __align__(16) unsigned short sbuf[512];

    // weight B-fragments (5 matrices x 4 k-tiles), exp2-prescaled
    bf16x8 wf[5][4];
    #pragma unroll
    for (int m = 0; m < 5; ++m)
        #pragma unroll
        for (int kt = 0; kt < 4; ++kt)
            wf[m][kt] = *(const bf16x8*)(wfrag + ((((size_t)m * 8 + w) * 4 + kt) * 64 + l) * 8);

    float bs1 = bsdf1[col] * (-L2E);
    float bs2 = bsdf2[col] * (-2.0f * L2E);
    float tp1a = Tp1[col], tp1b = Tp1[128 + col];   // pre-scaled -L2E
    float tp2a = Tp2[col], tp2b = Tp2[128 + col];   // pre-scaled -2L2E

    float h = h0[(size_t)(rb * 4 + g) * 128 + col];

    // LDS byte addresses. write (row=g, col): line = col>>3, line ^= g<<1
    int wline = ((col >> 3) ^ (g << 1)) & 15;
    char* pdw = (char*)dbuf + g * 256 + wline * 16 + (col & 7) * 2;
    char* psw = (char*)sbuf + g * 256 + wline * 16 + (col & 7) * 2;
    // read (rrow = cl&3, k-slice kt*32 + g*8): line = kt*4+g, ^= rrow<<1
    const bf16x8* prd[4]; const bf16x8* prs[4];
    int rrow = cl & 3;
    #pragma unroll
    for (int kt = 0; kt < 4; ++kt) {
        int off = rrow * 256 + (((kt * 4 + g) ^ (rrow << 1)) & 15) * 16;
        prd[kt] = (const bf16x8*)((char*)dbuf + off);
        prs[kt] = (const bf16x8*)((char*)sbuf + off);
    }

    const size_t TSTR = (size_t)NRB * 512;   // per-t stride in f32 elements
    const float* xp = xcd + (size_t)rb * 512 + tid;
    const float* kp = kipre + (size_t)rb * 512 + tid;
    const unsigned char* cp = cpkg + (size_t)rb * 512;

    // prefetch pipeline (depth 2; streams padded past t=501)
    float xn   = xp[TSTR];
    float xn2  = xp[2 * TSTR];
    float kip  = kp[0];
    float kip1 = kp[TSTR];
    unsigned char c0 = cp[0], c1v = cp[1];

    // y-partial pointer: ypart[((t*128+rb)*8 + w)*4 + g]
    float* ypt = ypart + (size_t)(rb * 8 + w) * 4 + g;
    const size_t YSTR = (size_t)NRB * 8 * 4;
    bool ystore = (cl == 0);

    // prologue: d0 = x(0) - h0
    {
        float x0 = xp[0];
        uint32_t pk = cvtpk(x0 - h, x0 - h);
        *(unsigned short*)pdw = (unsigned short)pk;
    }
    bar_lgkm();

    #pragma unroll 2
    for (int t = 0; t < TT; ++t) {
        // ---- prefetch (never waited before next barrier) ----
        float xn3  = xp[(size_t)(t + 3) * TSTR];
        float kip2 = kp[(size_t)(t + 2) * TSTR];
        unsigned char c2v = cp[t + 2];

        // ---- phase 1: s1,s2 = d@Wsdf (scaled); gd = d@(L2E*Wki0) ----
        f32x4 s1 = {bs1, bs1, bs1, bs1};
        f32x4 s2 = {bs2, bs2, bs2, bs2};
        f32x4 gd = {0.f, 0.f, 0.f, 0.f};
        #pragma unroll
        for (int kt = 0; kt < 4; ++kt) {
            bf16x8 df = *prd[kt];
            s1 = __builtin_amdgcn_mfma_f32_16x16x32_bf16(df, wf[0][kt], s1, 0, 0, 0);
            s2 = __builtin_amdgcn_mfma_f32_16x16x32_bf16(df, wf[1][kt], s2, 0, 0, 0);
            gd = __builtin_amdgcn_mfma_f32_16x16x32_bf16(df, wf[4][kt], gd, 0, 0, 0);
        }
        float s1v = sel4(s1, g), s2v = sel4(s2, g), gdv = sel4(gd, g);
        float gv = __builtin_amdgcn_rcpf(1.0f + __builtin_amdgcn_exp2f(gdv + kip));
        float e1 = __builtin_amdgcn_exp2f(s1v), e2 = __builtin_amdgcn_exp2f(s2v);
        float sdf = (1.0f - e2) * __builtin_amdgcn_rcpf((1.0f + e1) * (1.0f + e2));
        {
            uint32_t pk = cvtpk(sdf, sdf);
            *(unsigned short*)psw = (unsigned short)pk;
        }
        bar_lgkm();

        // ---- phase 2: p1,p2 = sdf@Wpka (scaled); own-row bias post-select ----
        f32x4 p1 = {0.f, 0.f, 0.f, 0.f};
        f32x4 p2 = {0.f, 0.f, 0.f, 0.f};
        #pragma unroll
        for (int kt = 0; kt < 4; ++kt) {
            bf16x8 sf = *prs[kt];
            p1 = __builtin_amdgcn_mfma_f32_16x16x32_bf16(sf, wf[2][kt], p1, 0, 0, 0);
            p2 = __builtin_amdgcn_mfma_f32_16x16x32_bf16(sf, wf[3][kt], p2, 0, 0, 0);
        }
        float p1v = sel4(p1, g), p2v = sel4(p2, g);
        unsigned int myb = (((unsigned int)c0) >> g) & 1u;
        float t1 = myb ? tp1b : tp1a;
        float t2 = myb ? tp2b : tp2a;
        float e1p = __builtin_amdgcn_exp2f(p1v + t1), e2p = __builtin_amdgcn_exp2f(p2v + t2);
        float pka = (1.0f - e2p) * __builtin_amdgcn_rcpf((1.0f + e1p) * (1.0f + e2p));
        h = gv * (h - pka) + pka;

        // ---- d-write for step t+1 IMMEDIATELY (critical path) ----
        {
            uint32_t pk = cvtpk(xn - h, xn - h);
            *(unsigned short*)pdw = (unsigned short)pk;
        }
        // ---- y partial (off critical path): 16-lane DPP sum, masked store ----
        float yv = sum16(xn * h);
        if (ystore) ypt[0] = yv;
        ypt += YSTR;
        bar_lgkm();

        // rotate prefetch pipeline
        xn = xn2; xn2 = xn3; kip = kip1; kip1 = kip2; c0 = c1v; c1v = c2v;
    }
}

// ---------------- final: y[b][t] = sigmoid(sum of 8 wave partials); y[:,499] = 0 ------
__global__ __launch_bounds__(256) void k_yfinal(const float* __restrict__ ypart, float* __restrict__ y)
{
    int id = blockIdx.x * 256 + threadIdx.x;
    if (id >= BB * SS) return;
    int b = id / SS, t = id - b * SS;
    if (t == TT) { y[id] = 0.0f; return; }
    int rb = b >> 2, r = b & 3;
    const float* base = ypart + ((size_t)t * NRB + rb) * 32 + r;
    float s = 0.0f;
    #pragma unroll
    for (int w = 0; w < 8; ++w) s += base[w * 4];
    y[id] = fsig(s);
}

// ---------------- launch ----------------
extern "C" void kernel_launch(void* const* d_in, const int* in_sizes, int n_in,
                              void* d_out, int out_size, void* d_ws, size_t ws_size,
                              hipStream_t stream) {
    const int* qs    = (const int*)d_in[0];
    const int* cs    = (const int*)d_in[1];
    const int* qds   = (const int*)d_in[2];
    const int* cds   = (const int*)d_in[3];
    const int* corr  = (const int*)d_in[4];
    const float* Eq    = (const float*)d_in[5];
    const float* Ec    = (const float*)d_in[6];
    const float* Eqd   = (const float*)d_in[7];
    const float* Ecd   = (const float*)d_in[8];
    const float* Ecorr = (const float*)d_in[9];
    const float* Wx    = (const float*)d_in[10];
    const float* bx    = (const float*)d_in[11];
    const float* Wsdf1 = (const float*)d_in[12];
    const float* bsdf1 = (const float*)d_in[13];
    const float* Wsdf2 = (const float*)d_in[14];
    const float* bsdf2 = (const float*)d_in[15];
    const float* Wpka1 = (const float*)d_in[16];
    const float* bpka1 = (const float*)d_in[17];
    const float* Wpka2 = (const float*)d_in[18];
    const float* bpka2 = (const float*)d_in[19];
    const float* Wki   = (const float*)d_in[20];
    const float* bki   = (const float*)d_in[21];
    const float* h0    = (const float*)d_in[22];

    char* base;
    if (ws_size >= TOTAL_WS) {
        base = (char*)d_ws;
    } else {
        void* p = nullptr;
        hipGetSymbolAddress(&p, HIP_SYMBOL(g_fb));
        base = (char*)p;
    }

    float* Txq   = (float*)(base + OFF_TXQ);
    float* Txc   = (float*)(base + OFF_TXC);
    float* Txqd  = (float*)(base + OFF_TXQD);
    float* Txcd  = (float*)(base + OFF_TXCD);
    float* TkiQd = (float*)(base + OFF_TKIQD);
    float* TkiCd = (float*)(base + OFF_TKICD);
    float* TkiCo = (float*)(base + OFF_TKICO);
    float* Tp1   = (float*)(base + OFF_TP1);
    float* Tp2   = (float*)(base + OFF_TP2);
    float* Txq2  = (float*)(base + OFF_TXQ2);
    float* Txc2  = (float*)(base + OFF_TXC2);
    unsigned short* wfrag = (unsigned short*)(base + OFF_WFRAG);
    unsigned char*  cpk   = (unsigned char*)(base + OFF_CPK);
    float* xcd   = (float*)(base + OFF_XCD);
    float* kipre = (float*)(base + OFF_KIPRE);
    float* ypart = (float*)(base + OFF_YPART);

    k_tables<<<10906, 128, 0, stream>>>(Eq, Ec, Eqd, Ecd, Ecorr, Wx, bx,
                                        Wpka1, bpka1, Wpka2, bpka2, Wki, bki,
                                        Txq, Txc, Txqd, Txcd, TkiQd, TkiCd, TkiCo, Tp1, Tp2);
    k_tables2<<<10700, 128, 0, stream>>>(Wki, Txq, Txc, Txqd, Txcd, Txq2, Txc2, TkiQd, TkiCd);
    k_wfrag<<<160, 64, 0, stream>>>(Wsdf1, Wsdf2, Wpka1, Wpka2, Wki, wfrag);
    k_gather<<<SS * NRB, 512, 0, stream>>>(qs, cs, qds, cds, corr,
                                           Txq, Txc, Txqd, Txcd, Txq2, Txc2,
                                           TkiQd, TkiCd, TkiCo, xcd, kipre, cpk);
    k_rec<<<NRB, 512, 0, stream>>>(xcd, kipre, cpk, wfrag, Tp1, Tp2,
                                   bsdf1, bsdf2, h0, ypart);
    k_yfinal<<<(BB * SS + 255) / 256, 256, 0, stream>>>(ypart, (float*)d_out);
}

// Round 7
// 550.033 us; speedup vs baseline: 2.5988x; 1.0144x over previous
//
#include <hip/hip_runtime.h>
#include <hip/hip_bf16.h>
#include <cstdint>
#include <cstddef>

// ---------------- problem constants ----------------
#define BB 512
#define SS 500
#define TT 499            // scan steps t = 0..498
#define NRB 256           // recurrence blocks (2 rows each)
#define L2E 1.4426950408889634f

typedef float  f32x4  __attribute__((ext_vector_type(4)));
typedef short  bf16x8 __attribute__((ext_vector_type(8)));

// ---------------- workspace layout (bytes) ----------------
static constexpr size_t OFF_TXQ   = 0;                 // 10000*128*4
static constexpr size_t OFF_TXC   = 5120000;           // 500*128*4
static constexpr size_t OFF_TXQD  = 5376000;           // 100*128*4
static constexpr size_t OFF_TXCD  = 5427200;           // 100*128*4
static constexpr size_t OFF_TKIQD = 5478400;           // 100*128*4 (+= Txqd@Wki0)
static constexpr size_t OFF_TKICD = 5529600;           // 100*128*4 (+= Txcd@Wki0)
static constexpr size_t OFF_TKICO = 5580800;           // 2*128*4 (pad 1024)
static constexpr size_t OFF_TP1   = 5581824;           // 2*128*4 (pad 1024), scaled -L2E
static constexpr size_t OFF_TP2   = 5582848;           // 2*128*4 (pad 1024), scaled -2*L2E
static constexpr size_t OFF_TXQ2  = 5583872;           // 10000*128*4 (Txq@Wki0)
static constexpr size_t OFF_TXC2  = 10703872;          // 500*128*4   (Txc@Wki0)
static constexpr size_t OFF_WFRAG = 10959872;          // 5*128*128*2 (pre-scaled bf16)
static constexpr size_t OFF_CPK   = 11123712;          // 256*512 bytes
static constexpr size_t OFF_XCD   = 11254784;          // 504*256*256*4 (1 f32/elem layout)
static constexpr size_t OFF_KIPRE = 143375360;         // 504*256*256*4 (scaled -L2E)
static constexpr size_t OFF_YPART = 275495936;         // 499*256*16*4
static constexpr size_t TOTAL_WS  = 283671552;

// fallback scratch if harness workspace is too small
__device__ unsigned char g_fb[TOTAL_WS];

// ---------------- helpers ----------------
__device__ __forceinline__ unsigned short f2bf(float f) {
    union { float f; uint32_t u; } v; v.f = f;
    uint32_t u = v.u;
    uint32_t r = u + 0x7FFFu + ((u >> 16) & 1u);
    return (unsigned short)(r >> 16);
}
__device__ __forceinline__ float fsig(float z) {
    return __builtin_amdgcn_rcpf(1.0f + __expf(-z));
}
// pack 2 f32 -> 2 bf16 (RTNE): dst.lo = cvt(lo), dst.hi = cvt(hi)
__device__ __forceinline__ uint32_t cvtpk(float lo, float hi) {
    uint32_t r;
    asm("v_cvt_pk_bf16_f32 %0, %1, %2" : "=v"(r) : "v"(lo), "v"(hi));
    return r;
}
// barrier that only orders LDS traffic (prefetch loads stay in flight)
__device__ __forceinline__ void bar_lgkm() {
    asm volatile("s_waitcnt lgkmcnt(0)" ::: "memory");
    __builtin_amdgcn_s_barrier();
}
// sum over each 16-lane group via DPP (quad xor1, xor2, half-mirror, mirror)
__device__ __forceinline__ float sum16(float x) {
    int a = __float_as_int(x);
    int b = __builtin_amdgcn_update_dpp(a, a, 0xB1, 0xF, 0xF, false);   // quad xor1
    float s = x + __int_as_float(b);
    int c = __float_as_int(s);
    int d = __builtin_amdgcn_update_dpp(c, c, 0x4E, 0xF, 0xF, false);   // quad xor2
    s += __int_as_float(d);
    int e = __float_as_int(s);
    int f = __builtin_amdgcn_update_dpp(e, e, 0x141, 0xF, 0xF, false);  // row_half_mirror
    s += __int_as_float(f);
    int gg = __float_as_int(s);
    int hh = __builtin_amdgcn_update_dpp(gg, gg, 0x140, 0xF, 0xF, false); // row_mirror
    return s + __int_as_float(hh);
}

// ---------------- P1: per-table GEMM products ----------------
__global__ __launch_bounds__(128) void k_tables(
    const float* __restrict__ Eq, const float* __restrict__ Ec,
    const float* __restrict__ Eqd, const float* __restrict__ Ecd,
    const float* __restrict__ Ecorr,
    const float* __restrict__ Wx,  const float* __restrict__ bx,
    const float* __restrict__ Wpka1, const float* __restrict__ bpka1,
    const float* __restrict__ Wpka2, const float* __restrict__ bpka2,
    const float* __restrict__ Wki, const float* __restrict__ bki,
    float* __restrict__ Txq, float* __restrict__ Txc,
    float* __restrict__ Txqd, float* __restrict__ Txcd,
    float* __restrict__ TkiQd, float* __restrict__ TkiCd, float* __restrict__ TkiCo,
    float* __restrict__ Tp1, float* __restrict__ Tp2)
{
    int blk = blockIdx.x;
    const float* A; const float* W; const float* bias = nullptr; float* out; int row;
    float oscale = 1.0f;
    if      (blk < 10000) { A = Eq;    row = blk;          W = Wx;              bias = bx;    out = Txq;  }
    else if (blk < 10500) { A = Ec;    row = blk - 10000;  W = Wx  + 128*128;                 out = Txc;  }
    else if (blk < 10600) { A = Eqd;   row = blk - 10500;  W = Wx  + 256*128;                 out = Txqd; }
    else if (blk < 10700) { A = Ecd;   row = blk - 10600;  W = Wx  + 384*128;                 out = Txcd; }
    else if (blk < 10800) { A = Eqd;   row = blk - 10700;  W = Wki + 256*128;                 out = TkiQd;}
    else if (blk < 10900) { A = Ecd;   row = blk - 10800;  W = Wki + 384*128;                 out = TkiCd;}
    else if (blk < 10902) { A = Ecorr; row = blk - 10900;  W = Wki + 128*128;   bias = bki;   out = TkiCo;}
    else if (blk < 10904) { A = Ecorr; row = blk - 10902;  W = Wpka1 + 128*128; bias = bpka1; out = Tp1;  oscale = -L2E; }
    else                  { A = Ecorr; row = blk - 10904;  W = Wpka2 + 128*128; bias = bpka2; out = Tp2;  oscale = -2.0f*L2E; }

    __shared__ float a[128];
    int c = threadIdx.x;
    a[c] = A[row * 128 + c];
    __syncthreads();
    float acc = bias ? bias[c] : 0.0f;
    #pragma unroll 8
    for (int k = 0; k < 128; ++k) acc += a[k] * W[k * 128 + c];
    out[row * 128 + c] = acc * oscale;
}

// ---------------- P1b: fold x@Wki0 into tables ----------------
__global__ __launch_bounds__(128) void k_tables2(
    const float* __restrict__ Wki,
    const float* __restrict__ Txq, const float* __restrict__ Txc,
    const float* __restrict__ Txqd, const float* __restrict__ Txcd,
    float* __restrict__ Txq2, float* __restrict__ Txc2,
    float* __restrict__ TkiQd, float* __restrict__ TkiCd)
{
    int blk = blockIdx.x;
    const float* A; float* out; int row; bool accum;
    if      (blk < 10000) { A = Txq;  row = blk;          out = Txq2;  accum = false; }
    else if (blk < 10500) { A = Txc;  row = blk - 10000;  out = Txc2;  accum = false; }
    else if (blk < 10600) { A = Txqd; row = blk - 10500;  out = TkiQd; accum = true;  }
    else                  { A = Txcd; row = blk - 10600;  out = TkiCd; accum = true;  }
    __shared__ float a[128];
    int c = threadIdx.x;
    a[c] = A[row * 128 + c];
    __syncthreads();
    float acc = accum ? out[row * 128 + c] : 0.0f;
    #pragma unroll 8
    for (int k = 0; k < 128; ++k) acc += a[k] * Wki[k * 128 + c];
    out[row * 128 + c] = acc;
}

// ---------------- P0: weight matrices -> MFMA B-fragments (bf16, exp2-prescaled) ----
// scales: Wsdf1 -L2E | Wsdf2 -2L2E | Wpka1 -L2E | Wpka2 -2L2E | Wki0 +L2E
__global__ __launch_bounds__(64) void k_wfrag(
    const float* __restrict__ Wsdf1, const float* __restrict__ Wsdf2,
    const float* __restrict__ Wpka1, const float* __restrict__ Wpka2,
    const float* __restrict__ Wki, unsigned short* __restrict__ wfrag)
{
    int bid = blockIdx.x;                 // 5 * 8 * 4 = 160
    int m = bid >> 5, w = (bid >> 2) & 7, kt = bid & 3;
    const float* W = (m == 0) ? Wsdf1 : (m == 1) ? Wsdf2 : (m == 2) ? Wpka1 : (m == 3) ? Wpka2 : Wki;
    float sgn = (m == 0) ? -L2E : (m == 1) ? -2.0f*L2E : (m == 2) ? -L2E : (m == 3) ? -2.0f*L2E : L2E;
    int l = threadIdx.x;
    int cc = w * 16 + (l & 15);
    int k0 = kt * 32 + ((l >> 4) << 3);
    unsigned short v[8];
    #pragma unroll
    for (int j = 0; j < 8; ++j) v[j] = f2bf(sgn * W[(size_t)(k0 + j) * 128 + cc]);
    unsigned short* dst = wfrag + ((( (size_t)m * 8 + w) * 4 + kt) * 64 + l) * 8;
    #pragma unroll
    for (int j = 0; j < 8; ++j) dst[j] = v[j];
}

// ---------------- P2: materialize x / kipre, 256 f32 per (t, rb) ----------------
// element index e = row*128 + col (row in 0..1, col in 0..127), b = rb*2 + row
__global__ __launch_bounds__(256) void k_gather(
    const int* __restrict__ qs, const int* __restrict__ cs,
    const int* __restrict__ qds, const int* __restrict__ cds, const int* __restrict__ corr,
    const float* __restrict__ Txq, const float* __restrict__ Txc,
    const float* __restrict__ Txqd, const float* __restrict__ Txcd,
    const float* __restrict__ Txq2, const float* __restrict__ Txc2,
    const float* __restrict__ TkiQd, const float* __restrict__ TkiCd, const float* __restrict__ TkiCo,
    float* __restrict__ xcd, float* __restrict__ kipre, unsigned char* __restrict__ cpk)
{
    int bid = blockIdx.x;            // bid = t*256 + rb
    int t = bid >> 8, rb = bid & 255;
    int tid = threadIdx.x;
    int row = tid >> 7;
    int col = tid & 127;
    int b = rb * 2 + row;

    int iq  = qs  [(size_t)b * SS + t];
    int ic  = cs  [(size_t)b * SS + t];
    int iqd = qds [(size_t)b * SS + t];
    int icd = cds [(size_t)b * SS + t];
    int ico = corr[(size_t)b * SS + t];

    float x = Txq [(size_t)iq  * 128 + col] + Txc [(size_t)ic  * 128 + col]
            + Txqd[(size_t)iqd * 128 + col] + Txcd[(size_t)icd * 128 + col];
    float k = (Txq2 [(size_t)iq  * 128 + col] + Txc2 [(size_t)ic  * 128 + col]
             + TkiQd[(size_t)iqd * 128 + col] + TkiCd[(size_t)icd * 128 + col]
             + TkiCo[(size_t)ico * 128 + col]) * (-L2E);

    xcd  [(size_t)bid * 256 + tid] = x;
    kipre[(size_t)bid * 256 + tid] = k;

    if (tid == 0) {
        unsigned char bpk = 0;
        #pragma unroll
        for (int r = 0; r < 2; ++r)
            bpk |= (unsigned char)((corr[(size_t)(rb * 2 + r) * SS + t] & 1) << r);
        cpk[(size_t)rb * 512 + t] = bpk;
    }
}

// ---------------- recurrence: 256 blocks x 512 threads (8 waves, 2 rows/block) --------
// Dup-8 A-tile: LDS holds 2 rows; fragment reads use rrow = cl&1, so physical A row p
// carries logical row p&1. C reg i = logical row i&1 for EVERY lane; each lane's owned
// element is (row = g&1, col = w*16+cl): ONE cndmask select per value. Lanes g>=2
// duplicate the elementwise work (identical values); LDS writes masked to g<2.
// MFMA accumulation split into two 2-chains (kt01, kt23) to halve dependent latency.
// LDS swizzle: byte addr = row*256 + (col*2 ^ (row<<6)); reads conflict-free (verified
// per kt: rrow0/rrow1 bank sets disjoint), writes 2-way (free).
__global__ __launch_bounds__(512, 2) void k_rec(
    const float* __restrict__ xcd, const float* __restrict__ kipre,
    const unsigned char* __restrict__ cpkg,
    const unsigned short* __restrict__ wfrag,
    const float* __restrict__ Tp1, const float* __restrict__ Tp2,
    const float* __restrict__ bsdf1, const float* __restrict__ bsdf2,
    const float* __restrict__ h0, float* __restrict__ ypart)
{
    int rb = blockIdx.x;
    int tid = threadIdx.x;
    int w = tid >> 6, l = tid & 63;
    int g = l >> 4, cl = l & 15;
    int col = w * 16 + cl;
    int row = g & 1;                 // owned logical row
    bool owner = (g < 2);            // non-dup lanes (do LDS writes / y stores)

    __shared__ __align__(16) unsigned short dbuf[256];   // 2 rows x 128 cols bf16
    __shared__ __align__(16) unsigned short sbuf[256];

    // weight B-fragments (5 matrices x 4 k-tiles), exp2-prescaled
    bf16x8 wf[5][4];
    #pragma unroll
    for (int m = 0; m < 5; ++m)
        #pragma unroll
        for (int kt = 0; kt < 4; ++kt)
            wf[m][kt] = *(const bf16x8*)(wfrag + ((((size_t)m * 8 + w) * 4 + kt) * 64 + l) * 8);

    float bs1 = bsdf1[col] * (-L2E);
    float bs2 = bsdf2[col] * (-2.0f * L2E);
    float tp1a = Tp1[col], tp1b = Tp1[128 + col];   // pre-scaled -L2E
    float tp2a = Tp2[col], tp2b = Tp2[128 + col];   // pre-scaled -2L2E

    float h = h0[(size_t)(rb * 2 + row) * 128 + col];

    // LDS byte addresses (swizzled)
    char* pdw = (char*)dbuf + row * 256 + ((col * 2) ^ (row << 6));
    char* psw = (char*)sbuf + row * 256 + ((col * 2) ^ (row << 6));
    const bf16x8* prd[4]; const bf16x8* prs[4];
    int rrow = cl & 1;
    #pragma unroll
    for (int kt = 0; kt < 4; ++kt) {
        int off = rrow * 256 + ((kt * 64 + g * 16) ^ (rrow << 6));
        prd[kt] = (const bf16x8*)((char*)dbuf + off);
        prs[kt] = (const bf16x8*)((char*)sbuf + off);
    }

    const size_t TSTR = (size_t)NRB * 256;   // per-t stride in f32 elements
    int eidx = row * 128 + col;
    const float* xp = xcd + (size_t)rb * 256 + eidx;
    const float* kp = kipre + (size_t)rb * 256 + eidx;
    const unsigned char* cp = cpkg + (size_t)rb * 512;

    // prefetch pipeline (depth 2; streams padded past t=501)
    float xn   = xp[TSTR];
    float xn2  = xp[2 * TSTR];
    float kip  = kp[0];
    float kip1 = kp[TSTR];
    unsigned char c0 = cp[0], c1v = cp[1];

    // y-partial pointer: ypart[t][rb][w*2 + row]
    float* ypt = ypart + (size_t)rb * 16 + w * 2 + row;
    const size_t YSTR = (size_t)NRB * 16;
    bool ystore = (owner && cl == 0);

    // prologue: d0 = x(0) - h0
    {
        float x0 = xp[0];
        uint32_t pk = cvtpk(x0 - h, x0 - h);
        if (owner) *(unsigned short*)pdw = (unsigned short)pk;
    }
    bar_lgkm();

    #pragma unroll 2
    for (int t = 0; t < TT; ++t) {
        // ---- prefetch (never waited before next barrier) ----
        float xn3  = xp[(size_t)(t + 3) * TSTR];
        float kip2 = kp[(size_t)(t + 2) * TSTR];
        unsigned char c2v = cp[t + 2];

        // ---- phase 1: s1,s2 = d@Wsdf (scaled); gd = d@(L2E*Wki0) ----
        // two independent 2-chains per matrix (kt01 / kt23), combined post-select
        f32x4 s1a = {bs1, bs1, bs1, bs1}, s1b = {0.f, 0.f, 0.f, 0.f};
        f32x4 s2a = {bs2, bs2, bs2, bs2}, s2b = {0.f, 0.f, 0.f, 0.f};
        f32x4 gda = {0.f, 0.f, 0.f, 0.f}, gdb = {0.f, 0.f, 0.f, 0.f};
        {
            bf16x8 d0 = *prd[0], d1 = *prd[1], d2 = *prd[2], d3 = *prd[3];
            s1a = __builtin_amdgcn_mfma_f32_16x16x32_bf16(d0, wf[0][0], s1a, 0, 0, 0);
            s2a = __builtin_amdgcn_mfma_f32_16x16x32_bf16(d0, wf[1][0], s2a, 0, 0, 0);
            gda = __builtin_amdgcn_mfma_f32_16x16x32_bf16(d0, wf[4][0], gda, 0, 0, 0);
            s1b = __builtin_amdgcn_mfma_f32_16x16x32_bf16(d2, wf[0][2], s1b, 0, 0, 0);
            s2b = __builtin_amdgcn_mfma_f32_16x16x32_bf16(d2, wf[1][2], s2b, 0, 0, 0);
            gdb = __builtin_amdgcn_mfma_f32_16x16x32_bf16(d2, wf[4][2], gdb, 0, 0, 0);
            s1a = __builtin_amdgcn_mfma_f32_16x16x32_bf16(d1, wf[0][1], s1a, 0, 0, 0);
            s2a = __builtin_amdgcn_mfma_f32_16x16x32_bf16(d1, wf[1][1], s2a, 0, 0, 0);
            gda = __builtin_amdgcn_mfma_f32_16x16x32_bf16(d1, wf[4][1], gda, 0, 0, 0);
            s1b = __builtin_amdgcn_mfma_f32_16x16x32_bf16(d3, wf[0][3], s1b, 0, 0, 0);
            s2b = __builtin_amdgcn_mfma_f32_16x16x32_bf16(d3, wf[1][3], s2b, 0, 0, 0);
            gdb = __builtin_amdgcn_mfma_f32_16x16x32_bf16(d3, wf[4][3], gdb, 0, 0, 0);
        }
        float s1v = (row ? s1a[1] : s1a[0]) + (row ? s1b[1] : s1b[0]);
        float s2v = (row ? s2a[1] : s2a[0]) + (row ? s2b[1] : s2b[0]);
        float gdv = (row ? gda[1] : gda[0]) + (row ? gdb[1] : gdb[0]);
        float gv = __builtin_amdgcn_rcpf(1.0f + __builtin_amdgcn_exp2f(gdv + kip));
        float e1 = __builtin_amdgcn_exp2f(s1v), e2 = __builtin_amdgcn_exp2f(s2v);
        float sdf = (1.0f - e2) * __builtin_amdgcn_rcpf((1.0f + e1) * (1.0f + e2));
        {
            uint32_t pk = cvtpk(sdf, sdf);
            if (owner) *(unsigned short*)psw = (unsigned short)pk;
        }
        bar_lgkm();

        // ---- phase 2: p1,p2 = sdf@Wpka (scaled); own-row bias post-select ----
        f32x4 p1a = {0.f, 0.f, 0.f, 0.f}, p1b = {0.f, 0.f, 0.f, 0.f};
        f32x4 p2a = {0.f, 0.f, 0.f, 0.f}, p2b = {0.f, 0.f, 0.f, 0.f};
        {
            bf16x8 f0 = *prs[0], f1 = *prs[1], f2 = *prs[2], f3 = *prs[3];
            p1a = __builtin_amdgcn_mfma_f32_16x16x32_bf16(f0, wf[2][0], p1a, 0, 0, 0);
            p2a = __builtin_amdgcn_mfma_f32_16x16x32_bf16(f0, wf[3][0], p2a, 0, 0, 0);
            p1b = __builtin_amdgcn_mfma_f32_16x16x32_bf16(f2, wf[2][2], p1b, 0, 0, 0);
            p2b = __builtin_amdgcn_mfma_f32_16x16x32_bf16(f2, wf[3][2], p2b, 0, 0, 0);
            p1a = __builtin_amdgcn_mfma_f32_16x16x32_bf16(f1, wf[2][1], p1a, 0, 0, 0);
            p2a = __builtin_amdgcn_mfma_f32_16x16x32_bf16(f1, wf[3][1], p2a, 0, 0, 0);
            p1b = __builtin_amdgcn_mfma_f32_16x16x32_bf16(f3, wf[2][3], p1b, 0, 0, 0);
            p2b = __builtin_amdgcn_mfma_f32_16x16x32_bf16(f3, wf[3][3], p2b, 0, 0, 0);
        }
        float p1v = (row ? p1a[1] : p1a[0]) + (row ? p1b[1] : p1b[0]);
        float p2v = (row ? p2a[1] : p2a[0]) + (row ? p2b[1] : p2b[0]);
        unsigned int myb = (((unsigned int)c0) >> row) & 1u;
        float t1 = myb ? tp1b : tp1a;
        float t2 = myb ? tp2b : tp2a;
        float e1p = __builtin_amdgcn_exp2f(p1v + t1), e2p = __builtin_amdgcn_exp2f(p2v + t2);
        float pka = (1.0f - e2p) * __builtin_amdgcn_rcpf((1.0f + e1p) * (1.0f + e2p));
        h = gv * (h - pka) + pka;

        // ---- d-write for step t+1 IMMEDIATELY (critical path) ----
        {
            uint32_t pk = cvtpk(xn - h, xn - h);
            if (owner) *(unsigned short*)pdw = (unsigned short)pk;
        }
        // ---- y partial (off critical path): 16-lane DPP sum, masked store ----
        float yv = sum16(xn * h);
        if (ystore) ypt[0] = yv;
        ypt += YSTR;
        bar_lgkm();

        // rotate prefetch pipeline
        xn = xn2; xn2 = xn3; kip = kip1; kip1 = kip2; c0 = c1v; c1v = c2v;
    }
}

// ---------------- final: y[b][t] = sigmoid(sum of 8 wave partials); y[:,499] = 0 ------
__global__ __launch_bounds__(256) void k_yfinal(const float* __restrict__ ypart, float* __restrict__ y)
{
    int id = blockIdx.x * 256 + threadIdx.x;
    if (id >= BB * SS) return;
    int b = id / SS, t = id - b * SS;
    if (t == TT) { y[id] = 0.0f; return; }
    int rb = b >> 1, r = b & 1;
    const float* base = ypart + (size_t)t * NRB * 16 + (size_t)rb * 16 + r;
    float s = 0.0f;
    #pragma unroll
    for (int w = 0; w < 8; ++w) s += base[w * 2];
    y[id] = fsig(s);
}

// ---------------- launch ----------------
extern "C" void kernel_launch(void* const* d_in, const int* in_sizes, int n_in,
                              void* d_out, int out_size, void* d_ws, size_t ws_size,
                              hipStream_t stream) {
    const int* qs    = (const int*)d_in[0];
    const int* cs    = (const int*)d_in[1];
    const int* qds   = (const int*)d_in[2];
    const int* cds   = (const int*)d_in[3];
    const int* corr  = (const int*)d_in[4];
    const float* Eq    = (const float*)d_in[5];
    const float* Ec    = (const float*)d_in[6];
    const float* Eqd   = (const float*)d_in[7];
    const float* Ecd   = (const float*)d_in[8];
    const float* Ecorr = (const float*)d_in[9];
    const float* Wx    = (const float*)d_in[10];
    const float* bx    = (const float*)d_in[11];
    const float* Wsdf1 = (const float*)d_in[12];
    const float* bsdf1 = (const float*)d_in[13];
    const float* Wsdf2 = (const float*)d_in[14];
    const float* bsdf2 = (const float*)d_in[15];
    const float* Wpka1 = (const float*)d_in[16];
    const float* bpka1 = (const float*)d_in[17];
    const float* Wpka2 = (const float*)d_in[18];
    const float* bpka2 = (const float*)d_in[19];
    const float* Wki   = (const float*)d_in[20];
    const float* bki   = (const float*)d_in[21];
    const float* h0    = (const float*)d_in[22];

    char* base;
    if (ws_size >= TOTAL_WS) {
        base = (char*)d_ws;
    } else {
        void* p = nullptr;
        hipGetSymbolAddress(&p, HIP_SYMBOL(g_fb));
        base = (char*)p;
    }

    float* Txq   = (float*)(base + OFF_TXQ);
    float* Txc   = (float*)(base + OFF_TXC);
    float* Txqd  = (float*)(base + OFF_TXQD);
    float* Txcd  = (float*)(base + OFF_TXCD);
    float* TkiQd = (float*)(base + OFF_TKIQD);
    float* TkiCd = (float*)(base + OFF_TKICD);
    float* TkiCo = (float*)(base + OFF_TKICO);
    float* Tp1   = (float*)(base + OFF_TP1);
    float* Tp2   = (float*)(base + OFF_TP2);
    float* Txq2  = (float*)(base + OFF_TXQ2);
    float* Txc2  = (float*)(base + OFF_TXC2);
    unsigned short* wfrag = (unsigned short*)(base + OFF_WFRAG);
    unsigned char*  cpk   = (unsigned char*)(base + OFF_CPK);
    float* xcd   = (float*)(base + OFF_XCD);
    float* kipre = (float*)(base + OFF_KIPRE);
    float* ypart = (float*)(base + OFF_YPART);

    k_tables<<<10906, 128, 0, stream>>>(Eq, Ec, Eqd, Ecd, Ecorr, Wx, bx,
                                        Wpka1, bpka1, Wpka2, bpka2, Wki, bki,
                                        Txq, Txc, Txqd, Txcd, TkiQd, TkiCd, TkiCo, Tp1, Tp2);
    k_tables2<<<10700, 128, 0, stream>>>(Wki, Txq, Txc, Txqd, Txcd, Txq2, Txc2, TkiQd, TkiCd);
    k_wfrag<<<160, 64, 0, stream>>>(Wsdf1, Wsdf2, Wpka1, Wpka2, Wki, wfrag);
    k_gather<<<SS * NRB, 256, 0, stream>>>(qs, cs, qds, cds, corr,
                                           Txq, Txc, Txqd, Txcd, Txq2, Txc2,
                                           TkiQd, TkiCd, TkiCo, xcd, kipre, cpk);
    k_rec<<<NRB, 512, 0, stream>>>(xcd, kipre, cpk, wfrag, Tp1, Tp2,
                                   bsdf1, bsdf2, h0, ypart);
    k_yfinal<<<(BB * SS + 255) / 256, 256, 0, stream>>>(ypart, (float*)d_out);
}